// Round 10
// baseline (163.824 us; speedup 1.0000x reference)
//
#include <hip/hip_runtime.h>

typedef __attribute__((ext_vector_type(8))) short s8v;
typedef __attribute__((ext_vector_type(4))) short s4v;
typedef __attribute__((ext_vector_type(4))) float f4v;

__device__ __forceinline__ short f2bf(float f){
  union { float f; unsigned u; } v; v.f = f;
  unsigned r = v.u + 0x7fffu + ((v.u >> 16) & 1u);
  return (short)(r >> 16);
}
__device__ __forceinline__ float bf2f(short s){
  union { unsigned u; float f; } v; v.u = ((unsigned)(unsigned short)s) << 16; return v.f;
}
__device__ __forceinline__ float bflo(unsigned v){ union{unsigned u;float f;}w; w.u = v<<16; return w.f; }
__device__ __forceinline__ float bfhi(unsigned v){ union{unsigned u;float f;}w; w.u = v & 0xffff0000u; return w.f; }
__device__ __forceinline__ void gload16(const void* g, void* l){
  __builtin_amdgcn_global_load_lds((const __attribute__((address_space(1))) unsigned int*)g,
                                   (__attribute__((address_space(3))) unsigned int*)l, 16, 0, 0);
}

// ---------------- unified prep: 4 W-transposes (z=0..3), x->bf16 (z=4..5), rel prep (block 0,0,3) ----------------
__global__ __launch_bounds__(256) void prep_k(const float* __restrict__ w_q, const float* __restrict__ w_k,
                                              const float* __restrict__ w_v, const float* __restrict__ w_o,
                                              const float* __restrict__ x, const float* __restrict__ rel,
                                              short* __restrict__ wqkvT, short* __restrict__ woT,
                                              short* __restrict__ xb, short* __restrict__ relb,
                                              short* __restrict__ relT){
  int z = blockIdx.z;
  if (z < 4){
    __shared__ float t[64][65];
    const float* in = (z==0) ? w_q : (z==1) ? w_k : (z==2) ? w_v : w_o;
    short* out = (z==3) ? woT : (wqkvT + ((size_t)z<<20));
    int c0 = blockIdx.x*64, r0 = blockIdx.y*64;
    int tx = threadIdx.x & 63, ty = threadIdx.x >> 6;
    #pragma unroll
    for (int i=0;i<16;i++){ int r = ty + i*4; t[r][tx] = in[(size_t)(r0+r)*1024 + c0+tx]; }
    __syncthreads();
    #pragma unroll
    for (int i=0;i<16;i++){ int cc = ty + i*4; out[(size_t)(c0+cc)*1024 + r0+tx] = f2bf(t[tx][cc]); }
    if (z==3 && blockIdx.x==0 && blockIdx.y==0){
      for (int e = threadIdx.x; e < 65*64; e += 256){
        int j = e >> 6, d = e & 63;
        short bv = f2bf(rel[e]);
        relb[e] = bv;
        relT[d*72 + j] = bv;
      }
    }
  } else {
    int bid = (z-4)*256 + blockIdx.y*16 + blockIdx.x;
    int i = bid*256 + threadIdx.x;
    #pragma unroll
    for (int p=0;p<4;p++){
      int idx = p*131072 + i;
      f4v v = ((const f4v*)x)[idx];
      s4v o; o[0]=f2bf(v[0]); o[1]=f2bf(v[1]); o[2]=f2bf(v[2]); o[3]=f2bf(v[3]);
      ((s4v*)xb)[idx] = o;
    }
  }
}

// ---- 128x128 GEMM core: global_load_lds(16B) with pre-swizzled SOURCE, linear LDS dest, XOR'd frag read ----
__device__ __forceinline__ void gemm128_core(const short* __restrict__ A, const short* __restrict__ Bt,
                                             int m0, int n0, short* As, short* Bs, f4v acc[4][4]){
  int tid = threadIdx.x;
  int lane = tid & 63, wave = tid >> 6;
  int wr = wave >> 1, wc = wave & 1, g = lane >> 4, c = lane & 15;
  int lrow = lane >> 3;                    // 0..7 within the 8-row stage chunk (== row&7)
  int scol = ((lane & 7) ^ lrow) * 8;      // inverse-swizzled global column
  for (int k0 = 0; k0 < 1024; k0 += 64){
    #pragma unroll
    for (int p=0;p<4;p++){
      int r0 = wave*32 + p*8;
      gload16(A  + (size_t)(m0 + r0 + lrow)*1024 + k0 + scol, &As[r0*64]);
      gload16(Bt + (size_t)(n0 + r0 + lrow)*1024 + k0 + scol, &Bs[r0*64]);
    }
    __syncthreads();
    #pragma unroll
    for (int ks=0;ks<2;ks++){
      s8v a[4], b[4];
      int pu = ((ks*4 + g) ^ (c & 7))*8;   // swizzled read back
      #pragma unroll
      for (int mi=0;mi<4;mi++) a[mi] = *(const s8v*)(&As[(wr*64 + mi*16 + c)*64 + pu]);
      #pragma unroll
      for (int ni=0;ni<4;ni++) b[ni] = *(const s8v*)(&Bs[(wc*64 + ni*16 + c)*64 + pu]);
      #pragma unroll
      for (int mi=0;mi<4;mi++)
        #pragma unroll
        for (int ni=0;ni<4;ni++)
          acc[mi][ni] = __builtin_amdgcn_mfma_f32_16x16x32_bf16(a[mi], b[ni], acc[mi][ni], 0,0,0);
    }
    __syncthreads();
  }
}

// ---------------- fused QKV GEMM (128^2): bias + RoPE + head-major/transposed layouts ----------------
__global__ __launch_bounds__(256) void gemm_qkv_k(const short* __restrict__ A, const short* __restrict__ Bt,
                                                  const float* __restrict__ b_q, const float* __restrict__ b_k,
                                                  const float* __restrict__ b_v,
                                                  const float* __restrict__ cs, const float* __restrict__ sn,
                                                  short* __restrict__ Qb, short* __restrict__ Kb,
                                                  short* __restrict__ Vt){
  __shared__ __align__(16) char lbuf[33792];
  short* As = (short*)lbuf;
  short* Bs = (short*)(lbuf + 16384);
  short* st = (short*)lbuf;
  int flat = blockIdx.x;                        // 384 blocks
  int swz = (flat & 7)*48 + (flat >> 3);
  int m0 = (swz / 24) * 128, n0 = (swz % 24) * 128;
  int lane = threadIdx.x & 63, wave = threadIdx.x >> 6;
  int wr = wave >> 1, wc = wave & 1, g = lane >> 4, c = lane & 15;
  f4v acc[4][4] = {};
  gemm128_core(A, Bt, m0, n0, As, Bs, acc);

  int sec = n0 >> 10;                           // 0=Q 1=K 2=V (uniform)
  const float* bias = (sec==0) ? b_q : (sec==1) ? b_k : b_v;
  int b = m0 >> 10, s0 = m0 & 1023, hbase = (n0 & 1023) >> 6;
  #pragma unroll
  for (int mi=0;mi<4;mi++)
    #pragma unroll
    for (int ni=0;ni<4;ni++){
      int cl = wc*64 + ni*16 + c;
      int hcol = (n0 & 1023) + cl;
      float bi = bias[hcol];
      int d = hcol & 63, ifr = d >> 1;
      #pragma unroll
      for (int i=0;i<4;i++){
        int rl = wr*64 + mi*16 + g*4 + i;
        float v = acc[mi][ni][i] + bi;
        if (sec < 2){
          int s = s0 + rl;
          float co = cs[s*32 + ifr], si = sn[s*32 + ifr];
          float p = __shfl_xor(v, 1, 64);
          float o = (cl & 1) ? fmaf(p, si, v*co) : fmaf(v, co, -(p*si));
          if (sec == 0) o *= 0.125f;
          v = o;
        }
        st[rl*132 + cl] = f2bf(v);
      }
    }
  __syncthreads();
  if (sec < 2){
    short* dst = (sec==0) ? Qb : Kb;
    for (int e = threadIdx.x; e < 128*32; e += 256){
      int row = e >> 5, cl4 = (e & 31)*4;
      int h = hbase + (cl4 >> 6), d = cl4 & 63;
      s4v o = *(const s4v*)(&st[row*132 + cl4]);
      *(s4v*)(&dst[((size_t)(b*16+h)*1024 + s0 + row)*64 + d]) = o;
    }
  } else {
    for (int e = threadIdx.x; e < 128*32; e += 256){
      int cl = e >> 5, s4 = (e & 31)*4;
      int h = hbase + (cl >> 6), dl = cl & 63;
      s4v o;
      o[0] = st[(s4+0)*132 + cl]; o[1] = st[(s4+1)*132 + cl];
      o[2] = st[(s4+2)*132 + cl]; o[3] = st[(s4+3)*132 + cl];
      *(s4v*)(&Vt[(size_t)(b*16+h)*65536 + (size_t)dl*1024 + s0 + s4]) = o;
    }
  }
}

// ---------------- out-proj GEMM (128^2): C f32 = A @ woT^T + b_o ----------------
__global__ __launch_bounds__(256) void gemm_out_k(const short* __restrict__ A, const short* __restrict__ Bt,
                                                  const float* __restrict__ bias, float* __restrict__ C){
  __shared__ __align__(16) short As[128*64];
  __shared__ __align__(16) short Bs[128*64];
  int flat = blockIdx.x;                        // 128 blocks
  int swz = (flat & 7)*16 + (flat >> 3);
  int n0 = (swz & 7)*128, m0 = (swz >> 3)*128;
  int lane = threadIdx.x & 63, wave = threadIdx.x >> 6;
  int wr = wave >> 1, wc = wave & 1, g = lane >> 4, c = lane & 15;
  f4v acc[4][4] = {};
  gemm128_core(A, Bt, m0, n0, As, Bs, acc);
  #pragma unroll
  for (int mi=0;mi<4;mi++)
    #pragma unroll
    for (int ni=0;ni<4;ni++){
      int col = n0 + wc*64 + ni*16 + c;
      float bi = bias[col];
      #pragma unroll
      for (int i=0;i<4;i++){
        int row = m0 + wr*64 + mi*16 + g*4 + i;
        C[(size_t)row*1024 + col] = acc[mi][ni][i] + bi;
      }
    }
}

// ---- fused attn: S^T reg scores + windowed rel bias + LDS-u barrier-free Newton + exact f32 step + PV ----
#define XSTR 1040
__global__ __launch_bounds__(256,4) void attn_fused_k(const short* __restrict__ Qb, const short* __restrict__ Kb,
                                                      const short* __restrict__ relb, const short* __restrict__ relT,
                                                      const short* __restrict__ Vt, short* __restrict__ ctxb){
  __shared__ __align__(16) short xbuf[16*XSTR];      // 33,280B: u bf16, later attn bf16 (same layout)
  __shared__ __align__(16) float wrow[16][68];       // 4,352B: buckets 0..64; [r][66] = theta-approx
  __shared__ __align__(16) short pb_b[16][66];       // 2,112B: pb bf16; red aliases post-scores
  float2* red = (float2*)&pb_b[0][0];                // [0..63] max/buckets, [64..127] final-step

  int lane = threadIdx.x & 63, wave = threadIdx.x >> 6;
  int g = lane >> 4, c = lane & 15;
  int flat = blockIdx.x;                              // 2048
  int swz = (flat & 7)*256 + (flat >> 3);
  int bh = swz >> 6, q0 = (swz & 63)*16;
  const short* Qh = Qb + (size_t)bh*65536;
  const short* Kh = Kb + (size_t)bh*65536;
  const short* Vh = Vt + (size_t)bh*65536;

  for (int e = threadIdx.x; e < 16*68; e += 256) ((float*)wrow)[e] = 0.f;

  s8v qa0 = *(const s8v*)(Qh + (q0+c)*64 + g*8);
  s8v qa1 = *(const s8v*)(Qh + (q0+c)*64 + 32 + g*8);

  // pb[r][j] = q_row(r) . rel_emb[j] via MFMA
  {
    int ntile = (wave==3) ? 2 : 1;
    for (int t=0; t<ntile; t++){
      int jt = (t==0) ? wave : 4;
      int j = jt*16 + c;
      s8v rb0 = {}, rb1 = {};
      if (j < 65){
        rb0 = *(const s8v*)(relb + j*64 + g*8);
        rb1 = *(const s8v*)(relb + j*64 + 32 + g*8);
      }
      f4v pa = {};
      pa = __builtin_amdgcn_mfma_f32_16x16x32_bf16(qa0, rb0, pa, 0,0,0);
      pa = __builtin_amdgcn_mfma_f32_16x16x32_bf16(qa1, rb1, pa, 0,0,0);
      if (j < 65){
        #pragma unroll
        for (int i=0;i<4;i++) pb_b[g*4+i][j] = f2bf(pa[i]);
      }
    }
  }
  __syncthreads();                                   // B1

  // scores^T: lane (g,c) holds S[q0+c][k], k = kc0 + t*16 + g*4 + i; windowed pb as C-init
  int q = q0 + c;
  int kc0 = wave*256;
  int Lb = q0 - 32 - kc0;
  int Ub = q0 + 47 - kc0;
  float pb0  = bf2f(pb_b[c][0]);
  float pb64 = bf2f(pb_b[c][64]);
  f4v x[16];
  #pragma unroll
  for (int t=0;t<16;t++){
    f4v ini;
    if (t*16+15 <= Lb){ ini[0]=pb0; ini[1]=pb0; ini[2]=pb0; ini[3]=pb0; }
    else if (t*16 >= Ub){ ini[0]=pb64; ini[1]=pb64; ini[2]=pb64; ini[3]=pb64; }
    else {
      #pragma unroll
      for (int i=0;i<4;i++){
        int k = kc0 + t*16 + g*4 + i;
        int jj = min(max(k - q, -32), 32) + 32;
        ini[i] = bf2f(pb_b[c][jj]);
      }
    }
    const short* kp = Kh + (kc0 + t*16 + c)*64 + g*8;
    s8v ka0 = *(const s8v*)(kp);
    s8v ka1 = *(const s8v*)(kp + 32);
    ini = __builtin_amdgcn_mfma_f32_16x16x32_bf16(ka0, qa0, ini, 0,0,0);
    x[t] = __builtin_amdgcn_mfma_f32_16x16x32_bf16(ka1, qa1, ini, 0,0,0);
  }
  __syncthreads();                                   // B2a: pb_b dead, red alias safe

  // row max (cross-wave via red)
  f4v m4 = x[0];
  #pragma unroll
  for (int t=1;t<16;t++){
    m4[0]=fmaxf(m4[0],x[t][0]); m4[1]=fmaxf(m4[1],x[t][1]);
    m4[2]=fmaxf(m4[2],x[t][2]); m4[3]=fmaxf(m4[3],x[t][3]);
  }
  float mx = fmaxf(fmaxf(m4[0],m4[1]), fmaxf(m4[2],m4[3]));
  mx = fmaxf(mx, __shfl_xor(mx, 16, 64));
  mx = fmaxf(mx, __shfl_xor(mx, 32, 64));
  if (g == 0) red[wave*16 + c] = make_float2(mx, 0.f);
  __syncthreads();                                   // B2b
  {
    float2 r0 = red[c], r1 = red[16+c], r2 = red[32+c], r3 = red[48+c];
    mx = fmaxf(fmaxf(r0.x, r1.x), fmaxf(r2.x, r3.x));
  }

  // u = x - mx -> bf16 into xbuf (row-major, same layout as later attn)
  {
    f4v mx4 = {mx,mx,mx,mx};
    #pragma unroll
    for (int t=0;t<16;t++){
      f4v u4 = x[t] - mx4;
      unsigned d0,d1;
      asm("v_cvt_pk_bf16_f32 %0, %1, %2" : "=v"(d0) : "v"(u4[0]), "v"(u4[1]));
      asm("v_cvt_pk_bf16_f32 %0, %1, %2" : "=v"(d1) : "v"(u4[2]), "v"(u4[3]));
      *(uint2*)(xbuf + c*XSTR + kc0 + t*16 + g*4) = make_uint2(d0,d1);
    }
  }
  __syncthreads();                                   // B3

  // barrier-free Newton: 16-lane group (wave,rl) owns row rr; re-read u from LDS each iter
  int rl = lane >> 4, rr = wave*4 + rl, cc = lane & 15;
  {
    float th = -2.0f;
    for (int it=0; it<7; it++){
      f4v th4 = {th,th,th,th};
      f4v s1v = {0.f,0.f,0.f,0.f}, s2v = {0.f,0.f,0.f,0.f};
      #pragma unroll
      for (int seg=0; seg<8; seg++){
        uint4 pkv = *(const uint4*)(xbuf + rr*XSTR + cc*8 + seg*128);
        f4v a, b;
        a[0]=bflo(pkv.x); a[1]=bfhi(pkv.x); a[2]=bflo(pkv.y); a[3]=bfhi(pkv.y);
        b[0]=bflo(pkv.z); b[1]=bfhi(pkv.z); b[2]=bflo(pkv.w); b[3]=bfhi(pkv.w);
        f4v da = a - th4, db = b - th4;
        f4v ta, tb;
        ta[0]=fmaxf(da[0],0.f); ta[1]=fmaxf(da[1],0.f); ta[2]=fmaxf(da[2],0.f); ta[3]=fmaxf(da[3],0.f);
        tb[0]=fmaxf(db[0],0.f); tb[1]=fmaxf(db[1],0.f); tb[2]=fmaxf(db[2],0.f); tb[3]=fmaxf(db[3],0.f);
        s1v += ta; s1v += tb;
        s2v += ta*ta; s2v += tb*tb;
      }
      float S1 = (s1v[0]+s1v[1])+(s1v[2]+s1v[3]);
      float S2 = (s2v[0]+s2v[1])+(s2v[2]+s2v[3]);
      S1 += __shfl_xor(S1, 1, 64); S2 += __shfl_xor(S2, 1, 64);
      S1 += __shfl_xor(S1, 2, 64); S2 += __shfl_xor(S2, 2, 64);
      S1 += __shfl_xor(S1, 4, 64); S2 += __shfl_xor(S2, 4, 64);
      S1 += __shfl_xor(S1, 8, 64); S2 += __shfl_xor(S2, 8, 64);
      th += (S2 - 4.0f)/(2.0f*S1);
    }
    if (cc == 0) wrow[rr][66] = th;
  }
  __syncthreads();                                   // B4

  // final exact f32 Newton step on original x (MFMA layout, cross-wave sums)
  float theta;
  {
    float thx = mx + wrow[c][66];
    f4v th4 = {thx,thx,thx,thx};
    f4v s1v = {0.f,0.f,0.f,0.f}, s2v = {0.f,0.f,0.f,0.f};
    #pragma unroll
    for (int t=0;t<16;t++){
      f4v d = x[t] - th4;
      f4v tt;
      tt[0]=fmaxf(d[0],0.f); tt[1]=fmaxf(d[1],0.f); tt[2]=fmaxf(d[2],0.f); tt[3]=fmaxf(d[3],0.f);
      s1v += tt;
      s2v += tt*tt;
    }
    float S1 = (s1v[0]+s1v[1])+(s1v[2]+s1v[3]);
    float S2 = (s2v[0]+s2v[1])+(s2v[2]+s2v[3]);
    S1 += __shfl_xor(S1, 16, 64); S2 += __shfl_xor(S2, 16, 64);
    S1 += __shfl_xor(S1, 32, 64); S2 += __shfl_xor(S2, 32, 64);
    if (g == 0) red[64 + wave*16 + c] = make_float2(S1, S2);
    __syncthreads();                                 // B5
    float2 r0 = red[64+c], r1 = red[64+16+c], r2 = red[64+32+c], r3 = red[64+48+c];
    S1 = (r0.x+r1.x)+(r2.x+r3.x);
    S2 = (r0.y+r1.y)+(r2.y+r3.y);
    theta = thx + (S2 - 4.0f)/(2.0f*S1);
  }

  // epilogue: attn bf16 overwrites xbuf (same addresses), windowed bucket weights from f32 x
  float w0p = 0.f, w64p = 0.f;
  {
    f4v th4 = {theta, theta, theta, theta};
    short* arow = xbuf + c*XSTR + kc0 + g*4;
    #pragma unroll
    for (int t=0;t<16;t++){
      f4v d = x[t] - th4;
      f4v tt;
      tt[0]=fmaxf(d[0],0.f); tt[1]=fmaxf(d[1],0.f); tt[2]=fmaxf(d[2],0.f); tt[3]=fmaxf(d[3],0.f);
      tt = tt*0.5f;
      f4v a = tt*tt;
      unsigned d0, d1;
      asm("v_cvt_pk_bf16_f32 %0, %1, %2" : "=v"(d0) : "v"(a[0]), "v"(a[1]));
      asm("v_cvt_pk_bf16_f32 %0, %1, %2" : "=v"(d1) : "v"(a[2]), "v"(a[3]));
      *(uint2*)(arow + t*16) = make_uint2(d0, d1);
      if (t*16+15 <= Lb)      w0p  += (a[0]+a[1])+(a[2]+a[3]);
      else if (t*16 >= Ub)    w64p += (a[0]+a[1])+(a[2]+a[3]);
      else {
        #pragma unroll
        for (int i=0;i<4;i++){
          int raw = kc0 + t*16 + g*4 + i - q;
          if (raw <= -32) w0p += a[i];
          else if (raw >= 32) w64p += a[i];
          else wrow[c][raw+32] = a[i];
        }
      }
    }
  }
  w0p += __shfl_xor(w0p, 16, 64); w64p += __shfl_xor(w64p, 16, 64);
  w0p += __shfl_xor(w0p, 32, 64); w64p += __shfl_xor(w64p, 32, 64);
  if (g == 0) red[wave*16 + c] = make_float2(w0p, w64p);
  __syncthreads();                                   // B6
  if (wave == 0 && g == 0){
    float2 r0 = red[c], r1 = red[16+c], r2 = red[32+c], r3 = red[48+c];
    wrow[c][0]  = (r0.x+r1.x)+(r2.x+r3.x);
    wrow[c][64] = (r0.y+r1.y)+(r2.y+r3.y);
  }
  __syncthreads();                                   // B7

  // PV: wave owns d-cols [wave*16,+16), full K=1024, dual accumulator; + rel-ctx via 2 MFMAs
  f4v acc0 = {}, acc1 = {};
  __builtin_amdgcn_s_setprio(1);
  #pragma unroll
  for (int kk=0; kk<32; kk+=2){
    s8v af0 = *(const s8v*)(&xbuf[c*XSTR + kk*32 + g*8]);
    s8v bf0 = *(const s8v*)(Vh + (size_t)(wave*16+c)*1024 + kk*32 + g*8);
    acc0 = __builtin_amdgcn_mfma_f32_16x16x32_bf16(af0, bf0, acc0, 0,0,0);
    s8v af1 = *(const s8v*)(&xbuf[c*XSTR + (kk+1)*32 + g*8]);
    s8v bf1 = *(const s8v*)(Vh + (size_t)(wave*16+c)*1024 + (kk+1)*32 + g*8);
    acc1 = __builtin_amdgcn_mfma_f32_16x16x32_bf16(af1, bf1, acc1, 0,0,0);
  }
  f4v acc = acc0 + acc1;
  {
    const float* wp = &wrow[c][0];
    f4v A0 = *(const f4v*)(wp + g*8);
    f4v A1 = *(const f4v*)(wp + g*8 + 4);
    f4v A2 = *(const f4v*)(wp + 32 + g*8);
    f4v A3 = *(const f4v*)(wp + 32 + g*8 + 4);
    union { unsigned u[4]; s8v v; } W0, W1;
    asm("v_cvt_pk_bf16_f32 %0, %1, %2" : "=v"(W0.u[0]) : "v"(A0[0]), "v"(A0[1]));
    asm("v_cvt_pk_bf16_f32 %0, %1, %2" : "=v"(W0.u[1]) : "v"(A0[2]), "v"(A0[3]));
    asm("v_cvt_pk_bf16_f32 %0, %1, %2" : "=v"(W0.u[2]) : "v"(A1[0]), "v"(A1[1]));
    asm("v_cvt_pk_bf16_f32 %0, %1, %2" : "=v"(W0.u[3]) : "v"(A1[2]), "v"(A1[3]));
    asm("v_cvt_pk_bf16_f32 %0, %1, %2" : "=v"(W1.u[0]) : "v"(A2[0]), "v"(A2[1]));
    asm("v_cvt_pk_bf16_f32 %0, %1, %2" : "=v"(W1.u[1]) : "v"(A2[2]), "v"(A2[3]));
    asm("v_cvt_pk_bf16_f32 %0, %1, %2" : "=v"(W1.u[2]) : "v"(A3[0]), "v"(A3[1]));
    asm("v_cvt_pk_bf16_f32 %0, %1, %2" : "=v"(W1.u[3]) : "v"(A3[2]), "v"(A3[3]));
    s8v rb0 = *(const s8v*)(relT + (wave*16+c)*72 + g*8);
    s8v rb1 = *(const s8v*)(relT + (wave*16+c)*72 + 32 + g*8);
    acc = __builtin_amdgcn_mfma_f32_16x16x32_bf16(W0.v, rb0, acc, 0,0,0);
    acc = __builtin_amdgcn_mfma_f32_16x16x32_bf16(W1.v, rb1, acc, 0,0,0);
  }
  __builtin_amdgcn_s_setprio(0);
  int b = bh >> 4, h = bh & 15, d = wave*16 + c;
  float rl64 = bf2f(relT[d*72 + 64]);
  #pragma unroll
  for (int i=0;i<4;i++){
    int r = g*4+i;
    float s = acc[i] + wrow[r][64]*rl64;
    ctxb[((size_t)(b*1024 + q0 + r))*1024 + h*64 + d] = f2bf(s);
  }
}

extern "C" void kernel_launch(void* const* d_in, const int* in_sizes, int n_in,
                              void* d_out, int out_size, void* d_ws, size_t ws_size,
                              hipStream_t stream) {
  (void)in_sizes; (void)n_in; (void)out_size; (void)ws_size;
  const float* x    = (const float*)d_in[0];
  const float* w_q  = (const float*)d_in[1];
  const float* b_q  = (const float*)d_in[2];
  const float* w_k  = (const float*)d_in[3];
  const float* b_k  = (const float*)d_in[4];
  const float* w_v  = (const float*)d_in[5];
  const float* b_v  = (const float*)d_in[6];
  const float* w_o  = (const float*)d_in[7];
  const float* b_o  = (const float*)d_in[8];
  const float* rel  = (const float*)d_in[9];
  const float* rcos = (const float*)d_in[10];
  const float* rsin = (const float*)d_in[11];
  float* out = (float*)d_out;

  char* w = (char*)d_ws;
  short* xb    = (short*)(w);                        // 4 MiB
  short* wqkvT = (short*)(w + ((size_t)4<<20));      // 6 MiB  [3072][1024]
  short* woT   = (short*)(w + ((size_t)10<<20));     // 2 MiB
  short* Qb    = (short*)(w + ((size_t)12<<20));     // 4 MiB
  short* Kb    = (short*)(w + ((size_t)16<<20));     // 4 MiB
  short* Vt    = (short*)(w + ((size_t)20<<20));     // 4 MiB
  short* ctxb  = (short*)(w + ((size_t)24<<20));     // 4 MiB
  short* relb  = (short*)(w + ((size_t)28<<20));     // 8.3 KB
  short* relT  = (short*)(w + ((size_t)28<<20) + 65536); // 9.2 KB

  prep_k<<<dim3(16,16,6), 256, 0, stream>>>(w_q, w_k, w_v, w_o, x, rel, wqkvT, woT, xb, relb, relT);
  gemm_qkv_k<<<384, 256, 0, stream>>>(xb, wqkvT, b_q, b_k, b_v, rcos, rsin, Qb, Kb, Vt);
  attn_fused_k<<<2048, 256, 0, stream>>>(Qb, Kb, relb, relT, Vt, ctxb);
  gemm_out_k<<<128, 256, 0, stream>>>(ctxb, woT, b_o, out);
}

// Round 11
// 125.452 us; speedup vs baseline: 1.3059x; 1.3059x over previous
//
#include <hip/hip_runtime.h>

typedef __attribute__((ext_vector_type(8))) short s8v;
typedef __attribute__((ext_vector_type(4))) short s4v;
typedef __attribute__((ext_vector_type(4))) float f4v;

__device__ __forceinline__ short f2bf(float f){
  union { float f; unsigned u; } v; v.f = f;
  unsigned r = v.u + 0x7fffu + ((v.u >> 16) & 1u);
  return (short)(r >> 16);
}
__device__ __forceinline__ float bf2f(short s){
  union { unsigned u; float f; } v; v.u = ((unsigned)(unsigned short)s) << 16; return v.f;
}
__device__ __forceinline__ void gload16(const void* g, void* l){
  __builtin_amdgcn_global_load_lds((const __attribute__((address_space(1))) unsigned int*)g,
                                   (__attribute__((address_space(3))) unsigned int*)l, 16, 0, 0);
}

// ---------------- unified prep: 4 W-transposes (z=0..3), x->bf16 (z=4..5), rel prep (block 0,0,3) ----------------
__global__ __launch_bounds__(256) void prep_k(const float* __restrict__ w_q, const float* __restrict__ w_k,
                                              const float* __restrict__ w_v, const float* __restrict__ w_o,
                                              const float* __restrict__ x, const float* __restrict__ rel,
                                              short* __restrict__ wqkvT, short* __restrict__ woT,
                                              short* __restrict__ xb, short* __restrict__ relb,
                                              short* __restrict__ relT){
  int z = blockIdx.z;
  if (z < 4){
    __shared__ float t[64][65];
    const float* in = (z==0) ? w_q : (z==1) ? w_k : (z==2) ? w_v : w_o;
    short* out = (z==3) ? woT : (wqkvT + ((size_t)z<<20));
    int c0 = blockIdx.x*64, r0 = blockIdx.y*64;
    int tx = threadIdx.x & 63, ty = threadIdx.x >> 6;
    #pragma unroll
    for (int i=0;i<16;i++){ int r = ty + i*4; t[r][tx] = in[(size_t)(r0+r)*1024 + c0+tx]; }
    __syncthreads();
    #pragma unroll
    for (int i=0;i<16;i++){ int cc = ty + i*4; out[(size_t)(c0+cc)*1024 + r0+tx] = f2bf(t[tx][cc]); }
    if (z==3 && blockIdx.x==0 && blockIdx.y==0){
      for (int e = threadIdx.x; e < 65*64; e += 256){
        int j = e >> 6, d = e & 63;
        short bv = f2bf(rel[e]);
        relb[e] = bv;
        relT[d*72 + j] = bv;
      }
    }
  } else {
    int bid = (z-4)*256 + blockIdx.y*16 + blockIdx.x;
    int i = bid*256 + threadIdx.x;
    #pragma unroll
    for (int p=0;p<4;p++){
      int idx = p*131072 + i;
      f4v v = ((const f4v*)x)[idx];
      s4v o; o[0]=f2bf(v[0]); o[1]=f2bf(v[1]); o[2]=f2bf(v[2]); o[3]=f2bf(v[3]);
      ((s4v*)xb)[idx] = o;
    }
  }
}

// ---- 128x64 GEMM core: global_load_lds(16B) with pre-swizzled SOURCE, linear LDS dest, XOR'd frag read ----
__device__ __forceinline__ void gemm12864_core(const short* __restrict__ A, const short* __restrict__ Bt,
                                               int m0, int n0, short* As, short* Bs, f4v acc[4][2]){
  int tid = threadIdx.x;
  int lane = tid & 63, wave = tid >> 6;
  int wr = wave >> 1, wc = wave & 1, g = lane >> 4, c = lane & 15;
  int lrow = lane >> 3;                    // 0..7 within the 8-row stage chunk (== row&7)
  int scol = ((lane & 7) ^ lrow) * 8;      // inverse-swizzled global column
  for (int k0 = 0; k0 < 1024; k0 += 64){
    #pragma unroll
    for (int p=0;p<4;p++){
      int r0 = wave*32 + p*8;
      gload16(A + (size_t)(m0 + r0 + lrow)*1024 + k0 + scol, &As[r0*64]);
    }
    #pragma unroll
    for (int p=0;p<2;p++){
      int r0 = wave*16 + p*8;
      gload16(Bt + (size_t)(n0 + r0 + lrow)*1024 + k0 + scol, &Bs[r0*64]);
    }
    __syncthreads();
    #pragma unroll
    for (int ks=0;ks<2;ks++){
      s8v a[4], b[2];
      int pu = ((ks*4 + g) ^ (c & 7))*8;   // swizzled read back
      #pragma unroll
      for (int mi=0;mi<4;mi++) a[mi] = *(const s8v*)(&As[(wr*64 + mi*16 + c)*64 + pu]);
      #pragma unroll
      for (int ni=0;ni<2;ni++) b[ni] = *(const s8v*)(&Bs[(wc*32 + ni*16 + c)*64 + pu]);
      #pragma unroll
      for (int mi=0;mi<4;mi++)
        #pragma unroll
        for (int ni=0;ni<2;ni++)
          acc[mi][ni] = __builtin_amdgcn_mfma_f32_16x16x32_bf16(a[mi], b[ni], acc[mi][ni], 0,0,0);
    }
    __syncthreads();
  }
}

// ---------------- fused QKV GEMM (128x64): bias + RoPE + head-major/transposed layouts ----------------
__global__ __launch_bounds__(256) void gemm_qkv_k(const short* __restrict__ A, const short* __restrict__ Bt,
                                                  const float* __restrict__ b_q, const float* __restrict__ b_k,
                                                  const float* __restrict__ b_v,
                                                  const float* __restrict__ cs, const float* __restrict__ sn,
                                                  short* __restrict__ Qb, short* __restrict__ Kb,
                                                  short* __restrict__ Vt){
  __shared__ __align__(16) char lbuf[24576];    // staging 16KB+8KB; epilogue st[128][66] bf16 (16896B)
  short* As = (short*)lbuf;
  short* Bs = (short*)(lbuf + 16384);
  short* st = (short*)lbuf;
  int flat = blockIdx.x;                        // 768 blocks
  int swz = (flat & 7)*96 + (flat >> 3);        // XCD-contiguous chunks (768%8==0)
  int m0 = (swz / 48) * 128, n0 = (swz % 48) * 64;
  int lane = threadIdx.x & 63, wave = threadIdx.x >> 6;
  int wr = wave >> 1, wc = wave & 1, g = lane >> 4, c = lane & 15;
  f4v acc[4][2] = {};
  gemm12864_core(A, Bt, m0, n0, As, Bs, acc);

  int sec = n0 >> 10;                           // 0=Q 1=K 2=V (uniform)
  const float* bias = (sec==0) ? b_q : (sec==1) ? b_k : b_v;
  int b = m0 >> 10, s0 = m0 & 1023, h0 = (n0 & 1023) >> 6;
  #pragma unroll
  for (int mi=0;mi<4;mi++)
    #pragma unroll
    for (int ni=0;ni<2;ni++){
      int cl = wc*32 + ni*16 + c;               // 0..63 == d
      float bi = bias[(n0 & 1023) + cl];
      int ifr = cl >> 1;
      #pragma unroll
      for (int i=0;i<4;i++){
        int rl = wr*64 + mi*16 + g*4 + i;       // 0..127 local row
        float v = acc[mi][ni][i] + bi;
        if (sec < 2){
          int s = s0 + rl;
          float co = cs[s*32 + ifr], si = sn[s*32 + ifr];
          float p = __shfl_xor(v, 1, 64);       // partner col cl^1 (lane c^1), same row
          float o = (cl & 1) ? fmaf(p, si, v*co) : fmaf(v, co, -(p*si));
          if (sec == 0) o *= 0.125f;
          v = o;
        }
        st[rl*66 + cl] = f2bf(v);
      }
    }
  __syncthreads();
  if (sec < 2){
    short* dst = (sec==0) ? Qb : Kb;
    size_t base = ((size_t)(b*16+h0)*1024 + s0)*64;
    for (int e = threadIdx.x; e < 128*16; e += 256){
      int row = e >> 4, cl4 = (e & 15)*4;
      s4v o = *(const s4v*)(&st[row*66 + cl4]);
      *(s4v*)(&dst[base + (size_t)row*64 + cl4]) = o;
    }
  } else {
    size_t base = (size_t)(b*16+h0)*65536;
    for (int e = threadIdx.x; e < 64*32; e += 256){
      int d = e >> 5, s4 = (e & 31)*4;
      s4v o;
      o[0] = st[(s4+0)*66 + d]; o[1] = st[(s4+1)*66 + d];
      o[2] = st[(s4+2)*66 + d]; o[3] = st[(s4+3)*66 + d];
      *(s4v*)(&Vt[base + (size_t)d*1024 + s0 + s4]) = o;
    }
  }
}

// ---------------- out-proj GEMM (128x64): C f32 = A @ woT^T + b_o ----------------
__global__ __launch_bounds__(256) void gemm_out_k(const short* __restrict__ A, const short* __restrict__ Bt,
                                                  const float* __restrict__ bias, float* __restrict__ C){
  __shared__ __align__(16) short As[128*64];
  __shared__ __align__(16) short Bs[64*64];
  int flat = blockIdx.x;                        // 256 blocks
  int swz = (flat & 7)*32 + (flat >> 3);
  int m0 = (swz >> 4)*128, n0 = (swz & 15)*64;
  int lane = threadIdx.x & 63, wave = threadIdx.x >> 6;
  int wr = wave >> 1, wc = wave & 1, g = lane >> 4, c = lane & 15;
  f4v acc[4][2] = {};
  gemm12864_core(A, Bt, m0, n0, As, Bs, acc);
  #pragma unroll
  for (int mi=0;mi<4;mi++)
    #pragma unroll
    for (int ni=0;ni<2;ni++){
      int col = n0 + wc*32 + ni*16 + c;
      float bi = bias[col];
      #pragma unroll
      for (int i=0;i<4;i++){
        int row = m0 + wr*64 + mi*16 + g*4 + i;
        C[(size_t)row*1024 + col] = acc[mi][ni][i] + bi;
      }
    }
}

// ---- fused attn (R7-proven): S^T reg scores + windowed rel bias + theta-fold Newton + PV + rel-ctx ----
#define ATPAD 1028
__global__ __launch_bounds__(256,4) void attn_fused_k(const short* __restrict__ Qb, const short* __restrict__ Kb,
                                                      const short* __restrict__ relb, const short* __restrict__ relT,
                                                      const short* __restrict__ Vt, short* __restrict__ ctxb){
  __shared__ __align__(16) short pb_b[16][66];       // q.rel^T bf16; later aliased as reduce scratch
  __shared__ __align__(16) float wrow[16][68];       // bucket weights f32
  __shared__ __align__(16) short attn_l[16][ATPAD];  // attn row-major bf16
  float2* red = (float2*)&pb_b[0][0];

  int lane = threadIdx.x & 63, wave = threadIdx.x >> 6;
  int g = lane >> 4, c = lane & 15;
  int flat = blockIdx.x;                              // 2048
  int swz = (flat & 7)*256 + (flat >> 3);
  int bh = swz >> 6, q0 = (swz & 63)*16;
  const short* Qh = Qb + (size_t)bh*65536;
  const short* Kh = Kb + (size_t)bh*65536;
  const short* Vh = Vt + (size_t)bh*65536;

  for (int e = threadIdx.x; e < 16*68; e += 256) ((float*)wrow)[e] = 0.f;

  s8v qa0 = *(const s8v*)(Qh + (q0+c)*64 + g*8);
  s8v qa1 = *(const s8v*)(Qh + (q0+c)*64 + 32 + g*8);

  // pb[r][j] = q_row(r) . rel_emb[j] via MFMA
  {
    int ntile = (wave==3) ? 2 : 1;
    for (int t=0; t<ntile; t++){
      int jt = (t==0) ? wave : 4;
      int j = jt*16 + c;
      s8v rb0 = {}, rb1 = {};
      if (j < 65){
        rb0 = *(const s8v*)(relb + j*64 + g*8);
        rb1 = *(const s8v*)(relb + j*64 + 32 + g*8);
      }
      f4v pa = {};
      pa = __builtin_amdgcn_mfma_f32_16x16x32_bf16(qa0, rb0, pa, 0,0,0);
      pa = __builtin_amdgcn_mfma_f32_16x16x32_bf16(qa1, rb1, pa, 0,0,0);
      if (j < 65){
        #pragma unroll
        for (int i=0;i<4;i++) pb_b[g*4+i][j] = f2bf(pa[i]);
      }
    }
  }
  __syncthreads();

  // scores^T: lane (g,c) holds S[q0+c][k], k = kc0 + t*16 + g*4 + i; windowed pb as C-init
  int q = q0 + c;
  int kc0 = wave*256;
  int Lb = q0 - 32 - kc0;
  int Ub = q0 + 47 - kc0;
  float pb0  = bf2f(pb_b[c][0]);
  float pb64 = bf2f(pb_b[c][64]);
  f4v x[16];
  #pragma unroll
  for (int t=0;t<16;t++){
    f4v ini;
    if (t*16+15 <= Lb){ ini[0]=pb0; ini[1]=pb0; ini[2]=pb0; ini[3]=pb0; }
    else if (t*16 >= Ub){ ini[0]=pb64; ini[1]=pb64; ini[2]=pb64; ini[3]=pb64; }
    else {
      #pragma unroll
      for (int i=0;i<4;i++){
        int k = kc0 + t*16 + g*4 + i;
        int jj = min(max(k - q, -32), 32) + 32;
        ini[i] = bf2f(pb_b[c][jj]);
      }
    }
    const short* kp = Kh + (kc0 + t*16 + c)*64 + g*8;
    s8v ka0 = *(const s8v*)(kp);
    s8v ka1 = *(const s8v*)(kp + 32);
    ini = __builtin_amdgcn_mfma_f32_16x16x32_bf16(ka0, qa0, ini, 0,0,0);
    x[t] = __builtin_amdgcn_mfma_f32_16x16x32_bf16(ka1, qa1, ini, 0,0,0);
  }
  __syncthreads();   // pb_b dead; red alias safe

  // row max
  f4v m4 = x[0];
  #pragma unroll
  for (int t=1;t<16;t++){
    m4[0]=fmaxf(m4[0],x[t][0]); m4[1]=fmaxf(m4[1],x[t][1]);
    m4[2]=fmaxf(m4[2],x[t][2]); m4[3]=fmaxf(m4[3],x[t][3]);
  }
  float mx = fmaxf(fmaxf(m4[0],m4[1]), fmaxf(m4[2],m4[3]));
  mx = fmaxf(mx, __shfl_xor(mx, 16, 64));
  mx = fmaxf(mx, __shfl_xor(mx, 32, 64));
  if (g == 0) red[wave*16 + c] = make_float2(mx, 0.f);
  __syncthreads();
  {
    float2 r0 = red[c], r1 = red[16+c], r2 = red[32+c], r3 = red[48+c];
    mx = fmaxf(fmaxf(r0.x, r1.x), fmaxf(r2.x, r3.x));
  }

  // theta-fold Newton (packed f32 math): theta = mx + 2*tau
  float theta = mx - 2.0f;
  for (int it=0; it<7; it++){
    f4v th4 = {theta, theta, theta, theta};
    f4v s1v = {0.f,0.f,0.f,0.f}, s2v = {0.f,0.f,0.f,0.f};
    #pragma unroll
    for (int t=0;t<16;t++){
      f4v d = x[t] - th4;
      f4v tt;
      tt[0]=fmaxf(d[0],0.f); tt[1]=fmaxf(d[1],0.f); tt[2]=fmaxf(d[2],0.f); tt[3]=fmaxf(d[3],0.f);
      s1v += tt;
      s2v += tt*tt;
    }
    float S1 = (s1v[0]+s1v[1])+(s1v[2]+s1v[3]);
    float S2 = (s2v[0]+s2v[1])+(s2v[2]+s2v[3]);
    S1 += __shfl_xor(S1, 16, 64); S2 += __shfl_xor(S2, 16, 64);
    S1 += __shfl_xor(S1, 32, 64); S2 += __shfl_xor(S2, 32, 64);
    int pp = (it+1)&1;
    if (g == 0) red[(pp*4 + wave)*16 + c] = make_float2(S1, S2);
    __syncthreads();
    float2 r0 = red[pp*64 + c], r1 = red[pp*64 + 16+c], r2 = red[pp*64 + 32+c], r3 = red[pp*64 + 48+c];
    S1 = (r0.x+r1.x)+(r2.x+r3.x);
    S2 = (r0.y+r1.y)+(r2.y+r3.y);
    theta += (S2 - 4.0f)/(2.0f*S1);
  }

  // epilogue: attn bf16 via v_cvt_pk -> LDS, windowed bucket weights
  float w0p = 0.f, w64p = 0.f;
  {
    f4v th4 = {theta, theta, theta, theta};
    short* arow = &attn_l[c][kc0 + g*4];
    #pragma unroll
    for (int t=0;t<16;t++){
      f4v d = x[t] - th4;
      f4v tt;
      tt[0]=fmaxf(d[0],0.f); tt[1]=fmaxf(d[1],0.f); tt[2]=fmaxf(d[2],0.f); tt[3]=fmaxf(d[3],0.f);
      tt = tt*0.5f;
      f4v a = tt*tt;
      unsigned d0, d1;
      asm("v_cvt_pk_bf16_f32 %0, %1, %2" : "=v"(d0) : "v"(a[0]), "v"(a[1]));
      asm("v_cvt_pk_bf16_f32 %0, %1, %2" : "=v"(d1) : "v"(a[2]), "v"(a[3]));
      *(uint2*)(arow + t*16) = make_uint2(d0, d1);
      if (t*16+15 <= Lb)      w0p  += (a[0]+a[1])+(a[2]+a[3]);
      else if (t*16 >= Ub)    w64p += (a[0]+a[1])+(a[2]+a[3]);
      else {
        #pragma unroll
        for (int i=0;i<4;i++){
          int raw = kc0 + t*16 + g*4 + i - q;
          if (raw <= -32) w0p += a[i];
          else if (raw >= 32) w64p += a[i];
          else wrow[c][raw+32] = a[i];
        }
      }
    }
  }
  w0p += __shfl_xor(w0p, 16, 64); w64p += __shfl_xor(w64p, 16, 64);
  w0p += __shfl_xor(w0p, 32, 64); w64p += __shfl_xor(w64p, 32, 64);
  if (g == 0) red[wave*16 + c] = make_float2(w0p, w64p);
  __syncthreads();
  if (wave == 0 && g == 0){
    float2 r0 = red[c], r1 = red[16+c], r2 = red[32+c], r3 = red[48+c];
    wrow[c][0]  = (r0.x+r1.x)+(r2.x+r3.x);
    wrow[c][64] = (r0.y+r1.y)+(r2.y+r3.y);
  }
  __syncthreads();

  // PV: wave owns d-cols [wave*16,+16), full K=1024; + rel-ctx via 2 MFMAs
  f4v acc = {};
  __builtin_amdgcn_s_setprio(1);
  #pragma unroll 8
  for (int kk=0; kk<32; kk++){
    s8v af = *(const s8v*)(&attn_l[c][kk*32 + g*8]);
    s8v bf = *(const s8v*)(Vh + (size_t)(wave*16+c)*1024 + kk*32 + g*8);
    acc = __builtin_amdgcn_mfma_f32_16x16x32_bf16(af, bf, acc, 0,0,0);
  }
  {
    const float* wp = &wrow[c][0];
    f4v A0 = *(const f4v*)(wp + g*8);
    f4v A1 = *(const f4v*)(wp + g*8 + 4);
    f4v A2 = *(const f4v*)(wp + 32 + g*8);
    f4v A3 = *(const f4v*)(wp + 32 + g*8 + 4);
    union { unsigned u[4]; s8v v; } W0, W1;
    asm("v_cvt_pk_bf16_f32 %0, %1, %2" : "=v"(W0.u[0]) : "v"(A0[0]), "v"(A0[1]));
    asm("v_cvt_pk_bf16_f32 %0, %1, %2" : "=v"(W0.u[1]) : "v"(A0[2]), "v"(A0[3]));
    asm("v_cvt_pk_bf16_f32 %0, %1, %2" : "=v"(W0.u[2]) : "v"(A1[0]), "v"(A1[1]));
    asm("v_cvt_pk_bf16_f32 %0, %1, %2" : "=v"(W0.u[3]) : "v"(A1[2]), "v"(A1[3]));
    asm("v_cvt_pk_bf16_f32 %0, %1, %2" : "=v"(W1.u[0]) : "v"(A2[0]), "v"(A2[1]));
    asm("v_cvt_pk_bf16_f32 %0, %1, %2" : "=v"(W1.u[1]) : "v"(A2[2]), "v"(A2[3]));
    asm("v_cvt_pk_bf16_f32 %0, %1, %2" : "=v"(W1.u[2]) : "v"(A3[0]), "v"(A3[1]));
    asm("v_cvt_pk_bf16_f32 %0, %1, %2" : "=v"(W1.u[3]) : "v"(A3[2]), "v"(A3[3]));
    s8v rb0 = *(const s8v*)(relT + (wave*16+c)*72 + g*8);
    s8v rb1 = *(const s8v*)(relT + (wave*16+c)*72 + 32 + g*8);
    acc = __builtin_amdgcn_mfma_f32_16x16x32_bf16(W0.v, rb0, acc, 0,0,0);
    acc = __builtin_amdgcn_mfma_f32_16x16x32_bf16(W1.v, rb1, acc, 0,0,0);
  }
  __builtin_amdgcn_s_setprio(0);
  int b = bh >> 4, h = bh & 15, d = wave*16 + c;
  float rl64 = bf2f(relT[d*72 + 64]);
  #pragma unroll
  for (int i=0;i<4;i++){
    int r = g*4+i;
    float s = acc[i] + wrow[r][64]*rl64;
    ctxb[((size_t)(b*1024 + q0 + r))*1024 + h*64 + d] = f2bf(s);
  }
}

extern "C" void kernel_launch(void* const* d_in, const int* in_sizes, int n_in,
                              void* d_out, int out_size, void* d_ws, size_t ws_size,
                              hipStream_t stream) {
  (void)in_sizes; (void)n_in; (void)out_size; (void)ws_size;
  const float* x    = (const float*)d_in[0];
  const float* w_q  = (const float*)d_in[1];
  const float* b_q  = (const float*)d_in[2];
  const float* w_k  = (const float*)d_in[3];
  const float* b_k  = (const float*)d_in[4];
  const float* w_v  = (const float*)d_in[5];
  const float* b_v  = (const float*)d_in[6];
  const float* w_o  = (const float*)d_in[7];
  const float* b_o  = (const float*)d_in[8];
  const float* rel  = (const float*)d_in[9];
  const float* rcos = (const float*)d_in[10];
  const float* rsin = (const float*)d_in[11];
  float* out = (float*)d_out;

  char* w = (char*)d_ws;
  short* xb    = (short*)(w);                        // 4 MiB
  short* wqkvT = (short*)(w + ((size_t)4<<20));      // 6 MiB  [3072][1024]
  short* woT   = (short*)(w + ((size_t)10<<20));     // 2 MiB
  short* Qb    = (short*)(w + ((size_t)12<<20));     // 4 MiB
  short* Kb    = (short*)(w + ((size_t)16<<20));     // 4 MiB
  short* Vt    = (short*)(w + ((size_t)20<<20));     // 4 MiB
  short* ctxb  = (short*)(w + ((size_t)24<<20));     // 4 MiB
  short* relb  = (short*)(w + ((size_t)28<<20));     // 8.3 KB
  short* relT  = (short*)(w + ((size_t)28<<20) + 65536); // 9.2 KB

  prep_k<<<dim3(16,16,6), 256, 0, stream>>>(w_q, w_k, w_v, w_o, x, rel, wqkvT, woT, xb, relb, relT);
  gemm_qkv_k<<<768, 256, 0, stream>>>(xb, wqkvT, b_q, b_k, b_v, rcos, rsin, Qb, Kb, Vt);
  attn_fused_k<<<2048, 256, 0, stream>>>(Qb, Kb, relb, relT, Vt, ctxb);
  gemm_out_k<<<256, 256, 0, stream>>>(ctxb, woT, b_o, out);
}

// Round 12
// 120.829 us; speedup vs baseline: 1.3558x; 1.0383x over previous
//
#include <hip/hip_runtime.h>

typedef __attribute__((ext_vector_type(8))) short s8v;
typedef __attribute__((ext_vector_type(4))) short s4v;
typedef __attribute__((ext_vector_type(4))) float f4v;

__device__ __forceinline__ short f2bf(float f){
  union { float f; unsigned u; } v; v.f = f;
  unsigned r = v.u + 0x7fffu + ((v.u >> 16) & 1u);
  return (short)(r >> 16);
}
__device__ __forceinline__ float bf2f(short s){
  union { unsigned u; float f; } v; v.u = ((unsigned)(unsigned short)s) << 16; return v.f;
}
__device__ __forceinline__ void gload16(const void* g, void* l){
  __builtin_amdgcn_global_load_lds((const __attribute__((address_space(1))) unsigned int*)g,
                                   (__attribute__((address_space(3))) unsigned int*)l, 16, 0, 0);
}

// ---------------- unified prep: 4 W-transposes (z=0..3), x->bf16 (z=4..5), rel prep (block 0,0,3) ----------------
__global__ __launch_bounds__(256) void prep_k(const float* __restrict__ w_q, const float* __restrict__ w_k,
                                              const float* __restrict__ w_v, const float* __restrict__ w_o,
                                              const float* __restrict__ x, const float* __restrict__ rel,
                                              short* __restrict__ wqkvT, short* __restrict__ woT,
                                              short* __restrict__ xb, short* __restrict__ relb,
                                              short* __restrict__ relT){
  int z = blockIdx.z;
  if (z < 4){
    __shared__ float t[64][65];
    const float* in = (z==0) ? w_q : (z==1) ? w_k : (z==2) ? w_v : w_o;
    short* out = (z==3) ? woT : (wqkvT + ((size_t)z<<20));
    int c0 = blockIdx.x*64, r0 = blockIdx.y*64;
    int tx = threadIdx.x & 63, ty = threadIdx.x >> 6;
    #pragma unroll
    for (int i=0;i<16;i++){ int r = ty + i*4; t[r][tx] = in[(size_t)(r0+r)*1024 + c0+tx]; }
    __syncthreads();
    #pragma unroll
    for (int i=0;i<16;i++){ int cc = ty + i*4; out[(size_t)(c0+cc)*1024 + r0+tx] = f2bf(t[tx][cc]); }
    if (z==3 && blockIdx.x==0 && blockIdx.y==0){
      for (int e = threadIdx.x; e < 65*64; e += 256){
        int j = e >> 6, d = e & 63;
        short bv = f2bf(rel[e]);
        relb[e] = bv;
        relT[d*72 + j] = bv;
      }
    }
  } else {
    int bid = (z-4)*256 + blockIdx.y*16 + blockIdx.x;
    int i = bid*256 + threadIdx.x;
    #pragma unroll
    for (int p=0;p<4;p++){
      int idx = p*131072 + i;
      f4v v = ((const f4v*)x)[idx];
      s4v o; o[0]=f2bf(v[0]); o[1]=f2bf(v[1]); o[2]=f2bf(v[2]); o[3]=f2bf(v[3]);
      ((s4v*)xb)[idx] = o;
    }
  }
}

// ---- 128x64 GEMM pieces: source-swizzled gload16 staging + XOR'd frag read; 2-buffer overlapped loop ----
__device__ __forceinline__ void stage12864(const short* __restrict__ A, const short* __restrict__ Bt,
                                           int m0, int n0, int k0, short* As, short* Bs,
                                           int wave, int lrow, int scol){
  #pragma unroll
  for (int p=0;p<4;p++){
    int r0 = wave*32 + p*8;
    gload16(A + (size_t)(m0 + r0 + lrow)*1024 + k0 + scol, &As[r0*64]);
  }
  #pragma unroll
  for (int p=0;p<2;p++){
    int r0 = wave*16 + p*8;
    gload16(Bt + (size_t)(n0 + r0 + lrow)*1024 + k0 + scol, &Bs[r0*64]);
  }
}
__device__ __forceinline__ void comp12864(const short* As, const short* Bs, f4v acc[4][2],
                                          int wr, int wc, int g, int c){
  #pragma unroll
  for (int ks=0;ks<2;ks++){
    s8v a[4], b[2];
    int pu = ((ks*4 + g) ^ (c & 7))*8;
    #pragma unroll
    for (int mi=0;mi<4;mi++) a[mi] = *(const s8v*)(&As[(wr*64 + mi*16 + c)*64 + pu]);
    #pragma unroll
    for (int ni=0;ni<2;ni++) b[ni] = *(const s8v*)(&Bs[(wc*32 + ni*16 + c)*64 + pu]);
    #pragma unroll
    for (int mi=0;mi<4;mi++)
      #pragma unroll
      for (int ni=0;ni<2;ni++)
        acc[mi][ni] = __builtin_amdgcn_mfma_f32_16x16x32_bf16(a[mi], b[ni], acc[mi][ni], 0,0,0);
  }
}

// ---------------- fused QKV GEMM (128x64, dbuf): bias + RoPE + head-major/transposed layouts ----------------
__global__ __launch_bounds__(256) void gemm_qkv_k(const short* __restrict__ A, const short* __restrict__ Bt,
                                                  const float* __restrict__ b_q, const float* __restrict__ b_k,
                                                  const float* __restrict__ b_v,
                                                  const float* __restrict__ cs, const float* __restrict__ sn,
                                                  short* __restrict__ Qb, short* __restrict__ Kb,
                                                  short* __restrict__ Vt){
  __shared__ __align__(16) char lbuf[49152];    // 2x(16KB A + 8KB B); epilogue st[128][66] (16896B) reuses
  short* As0 = (short*)lbuf;
  short* Bs0 = (short*)(lbuf + 16384);
  short* As1 = (short*)(lbuf + 24576);
  short* Bs1 = (short*)(lbuf + 40960);
  short* st  = (short*)lbuf;
  int flat = blockIdx.x;                        // 768 blocks
  int swz = (flat & 7)*96 + (flat >> 3);        // XCD-contiguous chunks (768%8==0)
  int m0 = (swz / 48) * 128, n0 = (swz % 48) * 64;
  int lane = threadIdx.x & 63, wave = threadIdx.x >> 6;
  int wr = wave >> 1, wc = wave & 1, g = lane >> 4, c = lane & 15;
  int lrow = lane >> 3, scol = ((lane & 7) ^ lrow)*8;
  f4v acc[4][2] = {};
  stage12864(A, Bt, m0, n0, 0, As0, Bs0, wave, lrow, scol);
  __syncthreads();
  #pragma unroll 2
  for (int t=0; t<16; t++){
    const short* Ac = (t&1) ? As1 : As0;
    const short* Bc = (t&1) ? Bs1 : Bs0;
    short* An = (t&1) ? As0 : As1;
    short* Bn = (t&1) ? Bs0 : Bs1;
    if (t < 15) stage12864(A, Bt, m0, n0, (t+1)*64, An, Bn, wave, lrow, scol);
    comp12864(Ac, Bc, acc, wr, wc, g, c);
    __syncthreads();
  }

  int sec = n0 >> 10;                           // 0=Q 1=K 2=V (uniform)
  const float* bias = (sec==0) ? b_q : (sec==1) ? b_k : b_v;
  int b = m0 >> 10, s0 = m0 & 1023, h0 = (n0 & 1023) >> 6;
  #pragma unroll
  for (int mi=0;mi<4;mi++)
    #pragma unroll
    for (int ni=0;ni<2;ni++){
      int cl = wc*32 + ni*16 + c;               // 0..63 == d
      float bi = bias[(n0 & 1023) + cl];
      int ifr = cl >> 1;
      #pragma unroll
      for (int i=0;i<4;i++){
        int rl = wr*64 + mi*16 + g*4 + i;       // 0..127 local row
        float v = acc[mi][ni][i] + bi;
        if (sec < 2){
          int s = s0 + rl;
          float co = cs[s*32 + ifr], si = sn[s*32 + ifr];
          float p = __shfl_xor(v, 1, 64);       // partner col cl^1 (lane c^1), same row
          float o = (cl & 1) ? fmaf(p, si, v*co) : fmaf(v, co, -(p*si));
          if (sec == 0) o *= 0.125f;
          v = o;
        }
        st[rl*66 + cl] = f2bf(v);
      }
    }
  __syncthreads();
  if (sec < 2){
    short* dst = (sec==0) ? Qb : Kb;
    size_t base = ((size_t)(b*16+h0)*1024 + s0)*64;
    for (int e = threadIdx.x; e < 128*16; e += 256){
      int row = e >> 4, cl4 = (e & 15)*4;
      s4v o = *(const s4v*)(&st[row*66 + cl4]);
      *(s4v*)(&dst[base + (size_t)row*64 + cl4]) = o;
    }
  } else {
    size_t base = (size_t)(b*16+h0)*65536;
    for (int e = threadIdx.x; e < 64*32; e += 256){
      int d = e >> 5, s4 = (e & 31)*4;
      s4v o;
      o[0] = st[(s4+0)*66 + d]; o[1] = st[(s4+1)*66 + d];
      o[2] = st[(s4+2)*66 + d]; o[3] = st[(s4+3)*66 + d];
      *(s4v*)(&Vt[base + (size_t)d*1024 + s0 + s4]) = o;
    }
  }
}

// ---------------- out-proj GEMM (64x64, dbuf, 512 blocks = 2/CU): C f32 = A @ woT^T + b_o ----------------
__device__ __forceinline__ void stage6464(const short* __restrict__ A, const short* __restrict__ Bt,
                                          int m0, int n0, int k0, short* As, short* Bs,
                                          int wave, int lrow, int scol){
  #pragma unroll
  for (int p=0;p<2;p++){
    int r0 = wave*16 + p*8;
    gload16(A  + (size_t)(m0 + r0 + lrow)*1024 + k0 + scol, &As[r0*64]);
    gload16(Bt + (size_t)(n0 + r0 + lrow)*1024 + k0 + scol, &Bs[r0*64]);
  }
}
__global__ __launch_bounds__(256) void gemm_out_k(const short* __restrict__ A, const short* __restrict__ Bt,
                                                  const float* __restrict__ bias, float* __restrict__ C){
  __shared__ __align__(16) short As0[64*64];
  __shared__ __align__(16) short Bs0[64*64];
  __shared__ __align__(16) short As1[64*64];
  __shared__ __align__(16) short Bs1[64*64];
  int flat = blockIdx.x;                        // 512 blocks
  int swz = (flat & 7)*64 + (flat >> 3);
  int m0 = (swz >> 4)*64, n0 = (swz & 15)*64;
  int lane = threadIdx.x & 63, wave = threadIdx.x >> 6;
  int wr = wave >> 1, wc = wave & 1, g = lane >> 4, c = lane & 15;
  int lrow = lane >> 3, scol = ((lane & 7) ^ lrow)*8;
  f4v acc[2][2] = {};
  stage6464(A, Bt, m0, n0, 0, As0, Bs0, wave, lrow, scol);
  __syncthreads();
  #pragma unroll 2
  for (int t=0; t<16; t++){
    const short* Ac = (t&1) ? As1 : As0;
    const short* Bc = (t&1) ? Bs1 : Bs0;
    short* An = (t&1) ? As0 : As1;
    short* Bn = (t&1) ? Bs0 : Bs1;
    if (t < 15) stage6464(A, Bt, m0, n0, (t+1)*64, An, Bn, wave, lrow, scol);
    #pragma unroll
    for (int ks=0;ks<2;ks++){
      s8v a[2], b[2];
      int pu = ((ks*4 + g) ^ (c & 7))*8;
      #pragma unroll
      for (int mi=0;mi<2;mi++) a[mi] = *(const s8v*)(&Ac[(wr*32 + mi*16 + c)*64 + pu]);
      #pragma unroll
      for (int ni=0;ni<2;ni++) b[ni] = *(const s8v*)(&Bc[(wc*32 + ni*16 + c)*64 + pu]);
      #pragma unroll
      for (int mi=0;mi<2;mi++)
        #pragma unroll
        for (int ni=0;ni<2;ni++)
          acc[mi][ni] = __builtin_amdgcn_mfma_f32_16x16x32_bf16(a[mi], b[ni], acc[mi][ni], 0,0,0);
    }
    __syncthreads();
  }
  #pragma unroll
  for (int mi=0;mi<2;mi++)
    #pragma unroll
    for (int ni=0;ni<2;ni++){
      int col = n0 + wc*32 + ni*16 + c;
      float bi = bias[col];
      #pragma unroll
      for (int i=0;i<4;i++){
        int row = m0 + wr*32 + mi*16 + g*4 + i;
        C[(size_t)row*1024 + col] = acc[mi][ni][i] + bi;
      }
    }
}

// ---- fused attn (R7 core): S^T reg scores + windowed rel bias + theta-fold Newton + V-prefetch PV ----
#define ATPAD 1028
__global__ __launch_bounds__(256,4) void attn_fused_k(const short* __restrict__ Qb, const short* __restrict__ Kb,
                                                      const short* __restrict__ relb, const short* __restrict__ relT,
                                                      const short* __restrict__ Vt, short* __restrict__ ctxb){
  __shared__ __align__(16) short pb_b[16][66];       // q.rel^T bf16; later aliased as reduce scratch
  __shared__ __align__(16) float wrow[16][68];       // in-window bucket weights f32 (j=1..63)
  __shared__ __align__(16) short attn_l[16][ATPAD];  // attn row-major bf16
  float2* red = (float2*)&pb_b[0][0];

  int lane = threadIdx.x & 63, wave = threadIdx.x >> 6;
  int g = lane >> 4, c = lane & 15;
  int flat = blockIdx.x;                              // 2048
  int swz = (flat & 7)*256 + (flat >> 3);
  int bh = swz >> 6, q0 = (swz & 63)*16;
  const short* Qh = Qb + (size_t)bh*65536;
  const short* Kh = Kb + (size_t)bh*65536;
  const short* Vh = Vt + (size_t)bh*65536;

  for (int e = threadIdx.x; e < 16*68; e += 256) ((float*)wrow)[e] = 0.f;

  s8v qa0 = *(const s8v*)(Qh + (q0+c)*64 + g*8);
  s8v qa1 = *(const s8v*)(Qh + (q0+c)*64 + 32 + g*8);

  // pb[r][j] = q_row(r) . rel_emb[j] via MFMA
  {
    int ntile = (wave==3) ? 2 : 1;
    for (int t=0; t<ntile; t++){
      int jt = (t==0) ? wave : 4;
      int j = jt*16 + c;
      s8v rb0 = {}, rb1 = {};
      if (j < 65){
        rb0 = *(const s8v*)(relb + j*64 + g*8);
        rb1 = *(const s8v*)(relb + j*64 + 32 + g*8);
      }
      f4v pa = {};
      pa = __builtin_amdgcn_mfma_f32_16x16x32_bf16(qa0, rb0, pa, 0,0,0);
      pa = __builtin_amdgcn_mfma_f32_16x16x32_bf16(qa1, rb1, pa, 0,0,0);
      if (j < 65){
        #pragma unroll
        for (int i=0;i<4;i++) pb_b[g*4+i][j] = f2bf(pa[i]);
      }
    }
  }
  __syncthreads();

  // scores^T: lane (g,c) holds S[q0+c][k], k = kc0 + t*16 + g*4 + i; windowed pb as C-init
  int q = q0 + c;
  int kc0 = wave*256;
  int Lb = q0 - 32 - kc0;
  int Ub = q0 + 47 - kc0;
  float pb0  = bf2f(pb_b[c][0]);
  float pb64 = bf2f(pb_b[c][64]);
  f4v x[16];
  __builtin_amdgcn_s_setprio(1);
  #pragma unroll
  for (int t=0;t<16;t++){
    f4v ini;
    if (t*16+15 <= Lb){ ini[0]=pb0; ini[1]=pb0; ini[2]=pb0; ini[3]=pb0; }
    else if (t*16 >= Ub){ ini[0]=pb64; ini[1]=pb64; ini[2]=pb64; ini[3]=pb64; }
    else {
      #pragma unroll
      for (int i=0;i<4;i++){
        int k = kc0 + t*16 + g*4 + i;
        int jj = min(max(k - q, -32), 32) + 32;
        ini[i] = bf2f(pb_b[c][jj]);
      }
    }
    const short* kp = Kh + (kc0 + t*16 + c)*64 + g*8;
    s8v ka0 = *(const s8v*)(kp);
    s8v ka1 = *(const s8v*)(kp + 32);
    ini = __builtin_amdgcn_mfma_f32_16x16x32_bf16(ka0, qa0, ini, 0,0,0);
    x[t] = __builtin_amdgcn_mfma_f32_16x16x32_bf16(ka1, qa1, ini, 0,0,0);
  }
  __builtin_amdgcn_s_setprio(0);

  // V prefetch: first 8 PV tiles into registers (latency hides under max+Newton)
  s8v vf[8];
  #pragma unroll
  for (int kk=0;kk<8;kk++)
    vf[kk] = *(const s8v*)(Vh + (size_t)(wave*16+c)*1024 + kk*32 + g*8);

  __syncthreads();   // pb_b dead; red alias safe

  // row max
  f4v m4 = x[0];
  #pragma unroll
  for (int t=1;t<16;t++){
    m4[0]=fmaxf(m4[0],x[t][0]); m4[1]=fmaxf(m4[1],x[t][1]);
    m4[2]=fmaxf(m4[2],x[t][2]); m4[3]=fmaxf(m4[3],x[t][3]);
  }
  float mx = fmaxf(fmaxf(m4[0],m4[1]), fmaxf(m4[2],m4[3]));
  mx = fmaxf(mx, __shfl_xor(mx, 16, 64));
  mx = fmaxf(mx, __shfl_xor(mx, 32, 64));
  if (g == 0) red[wave*16 + c] = make_float2(mx, 0.f);
  __syncthreads();
  {
    float2 r0 = red[c], r1 = red[16+c], r2 = red[32+c], r3 = red[48+c];
    mx = fmaxf(fmaxf(r0.x, r1.x), fmaxf(r2.x, r3.x));
  }

  // theta-fold Newton (packed f32 math): theta = mx + 2*tau
  float theta = mx - 2.0f;
  for (int it=0; it<7; it++){
    f4v th4 = {theta, theta, theta, theta};
    f4v s1v = {0.f,0.f,0.f,0.f}, s2v = {0.f,0.f,0.f,0.f};
    #pragma unroll
    for (int t=0;t<16;t++){
      f4v d = x[t] - th4;
      f4v tt;
      tt[0]=fmaxf(d[0],0.f); tt[1]=fmaxf(d[1],0.f); tt[2]=fmaxf(d[2],0.f); tt[3]=fmaxf(d[3],0.f);
      s1v += tt;
      s2v += tt*tt;
    }
    float S1 = (s1v[0]+s1v[1])+(s1v[2]+s1v[3]);
    float S2 = (s2v[0]+s2v[1])+(s2v[2]+s2v[3]);
    S1 += __shfl_xor(S1, 16, 64); S2 += __shfl_xor(S2, 16, 64);
    S1 += __shfl_xor(S1, 32, 64); S2 += __shfl_xor(S2, 32, 64);
    int pp = (it+1)&1;
    if (g == 0) red[(pp*4 + wave)*16 + c] = make_float2(S1, S2);
    __syncthreads();
    float2 r0 = red[pp*64 + c], r1 = red[pp*64 + 16+c], r2 = red[pp*64 + 32+c], r3 = red[pp*64 + 48+c];
    S1 = (r0.x+r1.x)+(r2.x+r3.x);
    S2 = (r0.y+r1.y)+(r2.y+r3.y);
    theta += (S2 - 4.0f)/(2.0f*S1);
  }

  // epilogue: attn bf16 via v_cvt_pk -> LDS, windowed bucket weights (j=0/64 partials stay in red)
  float w0p = 0.f, w64p = 0.f;
  {
    f4v th4 = {theta, theta, theta, theta};
    short* arow = &attn_l[c][kc0 + g*4];
    #pragma unroll
    for (int t=0;t<16;t++){
      f4v d = x[t] - th4;
      f4v tt;
      tt[0]=fmaxf(d[0],0.f); tt[1]=fmaxf(d[1],0.f); tt[2]=fmaxf(d[2],0.f); tt[3]=fmaxf(d[3],0.f);
      tt = tt*0.5f;
      f4v a = tt*tt;
      unsigned d0, d1;
      asm("v_cvt_pk_bf16_f32 %0, %1, %2" : "=v"(d0) : "v"(a[0]), "v"(a[1]));
      asm("v_cvt_pk_bf16_f32 %0, %1, %2" : "=v"(d1) : "v"(a[2]), "v"(a[3]));
      *(uint2*)(arow + t*16) = make_uint2(d0, d1);
      if (t*16+15 <= Lb)      w0p  += (a[0]+a[1])+(a[2]+a[3]);
      else if (t*16 >= Ub)    w64p += (a[0]+a[1])+(a[2]+a[3]);
      else {
        #pragma unroll
        for (int i=0;i<4;i++){
          int raw = kc0 + t*16 + g*4 + i - q;
          if (raw <= -32) w0p += a[i];
          else if (raw >= 32) w64p += a[i];
          else wrow[c][raw+32] = a[i];   // raw+32 in 1..63: slot 0 stays zero
        }
      }
    }
  }
  w0p += __shfl_xor(w0p, 16, 64); w64p += __shfl_xor(w64p, 16, 64);
  w0p += __shfl_xor(w0p, 32, 64); w64p += __shfl_xor(w64p, 32, 64);
  if (g == 0) red[wave*16 + c] = make_float2(w0p, w64p);   // per-wave partials; summed at store
  __syncthreads();                                         // B6: wrow+attn_l+red ready

  // PV: wave owns d-cols [wave*16,+16), full K=1024; first 8 tiles from vf regs; dual accumulator
  f4v acc0 = {}, acc1 = {};
  __builtin_amdgcn_s_setprio(1);
  #pragma unroll
  for (int kk=0; kk<8; kk+=2){
    s8v af0 = *(const s8v*)(&attn_l[c][kk*32 + g*8]);
    acc0 = __builtin_amdgcn_mfma_f32_16x16x32_bf16(af0, vf[kk], acc0, 0,0,0);
    s8v af1 = *(const s8v*)(&attn_l[c][(kk+1)*32 + g*8]);
    acc1 = __builtin_amdgcn_mfma_f32_16x16x32_bf16(af1, vf[kk+1], acc1, 0,0,0);
  }
  #pragma unroll
  for (int kk=8; kk<32; kk+=2){
    s8v af0 = *(const s8v*)(&attn_l[c][kk*32 + g*8]);
    s8v bf0 = *(const s8v*)(Vh + (size_t)(wave*16+c)*1024 + kk*32 + g*8);
    acc0 = __builtin_amdgcn_mfma_f32_16x16x32_bf16(af0, bf0, acc0, 0,0,0);
    s8v af1 = *(const s8v*)(&attn_l[c][(kk+1)*32 + g*8]);
    s8v bf1 = *(const s8v*)(Vh + (size_t)(wave*16+c)*1024 + (kk+1)*32 + g*8);
    acc1 = __builtin_amdgcn_mfma_f32_16x16x32_bf16(af1, bf1, acc1, 0,0,0);
  }
  f4v acc = acc0 + acc1;
  {
    const float* wp = &wrow[c][0];
    f4v A0 = *(const f4v*)(wp + g*8);
    f4v A1 = *(const f4v*)(wp + g*8 + 4);
    f4v A2 = *(const f4v*)(wp + 32 + g*8);
    f4v A3 = *(const f4v*)(wp + 32 + g*8 + 4);
    union { unsigned u[4]; s8v v; } W0, W1;
    asm("v_cvt_pk_bf16_f32 %0, %1, %2" : "=v"(W0.u[0]) : "v"(A0[0]), "v"(A0[1]));
    asm("v_cvt_pk_bf16_f32 %0, %1, %2" : "=v"(W0.u[1]) : "v"(A0[2]), "v"(A0[3]));
    asm("v_cvt_pk_bf16_f32 %0, %1, %2" : "=v"(W0.u[2]) : "v"(A1[0]), "v"(A1[1]));
    asm("v_cvt_pk_bf16_f32 %0, %1, %2" : "=v"(W0.u[3]) : "v"(A1[2]), "v"(A1[3]));
    asm("v_cvt_pk_bf16_f32 %0, %1, %2" : "=v"(W1.u[0]) : "v"(A2[0]), "v"(A2[1]));
    asm("v_cvt_pk_bf16_f32 %0, %1, %2" : "=v"(W1.u[1]) : "v"(A2[2]), "v"(A2[3]));
    asm("v_cvt_pk_bf16_f32 %0, %1, %2" : "=v"(W1.u[2]) : "v"(A3[0]), "v"(A3[1]));
    asm("v_cvt_pk_bf16_f32 %0, %1, %2" : "=v"(W1.u[3]) : "v"(A3[2]), "v"(A3[3]));
    s8v rb0 = *(const s8v*)(relT + (wave*16+c)*72 + g*8);
    s8v rb1 = *(const s8v*)(relT + (wave*16+c)*72 + 32 + g*8);
    acc = __builtin_amdgcn_mfma_f32_16x16x32_bf16(W0.v, rb0, acc, 0,0,0);
    acc = __builtin_amdgcn_mfma_f32_16x16x32_bf16(W1.v, rb1, acc, 0,0,0);
  }
  __builtin_amdgcn_s_setprio(0);

  // store: add j=0 and j=64 bucket terms (cross-wave partial sums read directly from red)
  int b = bh >> 4, h = bh & 15, d = wave*16 + c;
  float rl0  = bf2f(relT[d*72 + 0]);
  float rl64 = bf2f(relT[d*72 + 64]);
  #pragma unroll
  for (int i=0;i<4;i++){
    int r = g*4+i;
    float2 p0 = red[r], p1 = red[16+r], p2 = red[32+r], p3 = red[48+r];
    float w0 = (p0.x+p1.x)+(p2.x+p3.x);
    float w64v = (p0.y+p1.y)+(p2.y+p3.y);
    float s = acc[i] + w0*rl0 + w64v*rl64;
    ctxb[((size_t)(b*1024 + q0 + r))*1024 + h*64 + d] = f2bf(s);
  }
}

extern "C" void kernel_launch(void* const* d_in, const int* in_sizes, int n_in,
                              void* d_out, int out_size, void* d_ws, size_t ws_size,
                              hipStream_t stream) {
  (void)in_sizes; (void)n_in; (void)out_size; (void)ws_size;
  const float* x    = (const float*)d_in[0];
  const float* w_q  = (const float*)d_in[1];
  const float* b_q  = (const float*)d_in[2];
  const float* w_k  = (const float*)d_in[3];
  const float* b_k  = (const float*)d_in[4];
  const float* w_v  = (const float*)d_in[5];
  const float* b_v  = (const float*)d_in[6];
  const float* w_o  = (const float*)d_in[7];
  const float* b_o  = (const float*)d_in[8];
  const float* rel  = (const float*)d_in[9];
  const float* rcos = (const float*)d_in[10];
  const float* rsin = (const float*)d_in[11];
  float* out = (float*)d_out;

  char* w = (char*)d_ws;
  short* xb    = (short*)(w);                        // 4 MiB
  short* wqkvT = (short*)(w + ((size_t)4<<20));      // 6 MiB  [3072][1024]
  short* woT   = (short*)(w + ((size_t)10<<20));     // 2 MiB
  short* Qb    = (short*)(w + ((size_t)12<<20));     // 4 MiB
  short* Kb    = (short*)(w + ((size_t)16<<20));     // 4 MiB
  short* Vt    = (short*)(w + ((size_t)20<<20));     // 4 MiB
  short* ctxb  = (short*)(w + ((size_t)24<<20));     // 4 MiB
  short* relb  = (short*)(w + ((size_t)28<<20));     // 8.3 KB
  short* relT  = (short*)(w + ((size_t)28<<20) + 65536); // 9.2 KB

  prep_k<<<dim3(16,16,6), 256, 0, stream>>>(w_q, w_k, w_v, w_o, x, rel, wqkvT, woT, xb, relb, relT);
  gemm_qkv_k<<<768, 256, 0, stream>>>(xb, wqkvT, b_q, b_k, b_v, rcos, rsin, Qb, Kb, Vt);
  attn_fused_k<<<2048, 256, 0, stream>>>(Qb, Kb, relb, relT, Vt, ctxb);
  gemm_out_k<<<512, 256, 0, stream>>>(ctxb, woT, b_o, out);
}

// Round 14
// 120.755 us; speedup vs baseline: 1.3567x; 1.0006x over previous
//
#include <hip/hip_runtime.h>

typedef __attribute__((ext_vector_type(8))) short s8v;
typedef __attribute__((ext_vector_type(4))) short s4v;
typedef __attribute__((ext_vector_type(4))) float f4v;

__device__ __forceinline__ short f2bf(float f){
  union { float f; unsigned u; } v; v.f = f;
  unsigned r = v.u + 0x7fffu + ((v.u >> 16) & 1u);
  return (short)(r >> 16);
}
__device__ __forceinline__ float bf2f(short s){
  union { unsigned u; float f; } v; v.u = ((unsigned)(unsigned short)s) << 16; return v.f;
}
__device__ __forceinline__ void gload16(const void* g, void* l){
  __builtin_amdgcn_global_load_lds((const __attribute__((address_space(1))) unsigned int*)g,
                                   (__attribute__((address_space(3))) unsigned int*)l, 16, 0, 0);
}

// ---------------- unified prep: 4 W-transposes (z=0..3), x->bf16 (z=4..5), rel prep (block 0,0,3) ----------------
__global__ __launch_bounds__(256) void prep_k(const float* __restrict__ w_q, const float* __restrict__ w_k,
                                              const float* __restrict__ w_v, const float* __restrict__ w_o,
                                              const float* __restrict__ x, const float* __restrict__ rel,
                                              short* __restrict__ wqkvT, short* __restrict__ woT,
                                              short* __restrict__ xb, short* __restrict__ relb,
                                              short* __restrict__ relT){
  int z = blockIdx.z;
  if (z < 4){
    __shared__ float t[64][65];
    const float* in = (z==0) ? w_q : (z==1) ? w_k : (z==2) ? w_v : w_o;
    short* out = (z==3) ? woT : (wqkvT + ((size_t)z<<20));
    int c0 = blockIdx.x*64, r0 = blockIdx.y*64;
    int tx = threadIdx.x & 63, ty = threadIdx.x >> 6;
    #pragma unroll
    for (int i=0;i<16;i++){ int r = ty + i*4; t[r][tx] = in[(size_t)(r0+r)*1024 + c0+tx]; }
    __syncthreads();
    #pragma unroll
    for (int i=0;i<16;i++){ int cc = ty + i*4; out[(size_t)(c0+cc)*1024 + r0+tx] = f2bf(t[tx][cc]); }
    if (z==3 && blockIdx.x==0 && blockIdx.y==0){
      for (int e = threadIdx.x; e < 65*64; e += 256){
        int j = e >> 6, d = e & 63;
        short bv = f2bf(rel[e]);
        relb[e] = bv;
        relT[d*72 + j] = bv;
      }
    }
  } else {
    int bid = (z-4)*256 + blockIdx.y*16 + blockIdx.x;
    int i = bid*256 + threadIdx.x;
    #pragma unroll
    for (int p=0;p<4;p++){
      int idx = p*131072 + i;
      f4v v = ((const f4v*)x)[idx];
      s4v o; o[0]=f2bf(v[0]); o[1]=f2bf(v[1]); o[2]=f2bf(v[2]); o[3]=f2bf(v[3]);
      ((s4v*)xb)[idx] = o;
    }
  }
}

// ---- 128x64 GEMM pieces: source-swizzled gload16 staging + XOR'd frag read; 2-buffer overlapped loop ----
__device__ __forceinline__ void stage12864(const short* __restrict__ A, const short* __restrict__ Bt,
                                           int m0, int n0, int k0, short* As, short* Bs,
                                           int wave, int lrow, int scol){
  #pragma unroll
  for (int p=0;p<4;p++){
    int r0 = wave*32 + p*8;
    gload16(A + (size_t)(m0 + r0 + lrow)*1024 + k0 + scol, &As[r0*64]);
  }
  #pragma unroll
  for (int p=0;p<2;p++){
    int r0 = wave*16 + p*8;
    gload16(Bt + (size_t)(n0 + r0 + lrow)*1024 + k0 + scol, &Bs[r0*64]);
  }
}
__device__ __forceinline__ void comp12864(const short* As, const short* Bs, f4v acc[4][2],
                                          int wr, int wc, int g, int c){
  #pragma unroll
  for (int ks=0;ks<2;ks++){
    s8v a[4], b[2];
    int pu = ((ks*4 + g) ^ (c & 7))*8;
    #pragma unroll
    for (int mi=0;mi<4;mi++) a[mi] = *(const s8v*)(&As[(wr*64 + mi*16 + c)*64 + pu]);
    #pragma unroll
    for (int ni=0;ni<2;ni++) b[ni] = *(const s8v*)(&Bs[(wc*32 + ni*16 + c)*64 + pu]);
    #pragma unroll
    for (int mi=0;mi<4;mi++)
      #pragma unroll
      for (int ni=0;ni<2;ni++)
        acc[mi][ni] = __builtin_amdgcn_mfma_f32_16x16x32_bf16(a[mi], b[ni], acc[mi][ni], 0,0,0);
  }
}

// ---------------- fused QKV GEMM (128x64, dbuf): bias + RoPE + head-major/transposed layouts ----------------
__global__ __launch_bounds__(256) void gemm_qkv_k(const short* __restrict__ A, const short* __restrict__ Bt,
                                                  const float* __restrict__ b_q, const float* __restrict__ b_k,
                                                  const float* __restrict__ b_v,
                                                  const float* __restrict__ cs, const float* __restrict__ sn,
                                                  short* __restrict__ Qb, short* __restrict__ Kb,
                                                  short* __restrict__ Vt){
  __shared__ __align__(16) char lbuf[49152];    // 2x(16KB A + 8KB B); epilogue st[128][66] (16896B) reuses
  short* As0 = (short*)lbuf;
  short* Bs0 = (short*)(lbuf + 16384);
  short* As1 = (short*)(lbuf + 24576);
  short* Bs1 = (short*)(lbuf + 40960);
  short* st  = (short*)lbuf;
  int flat = blockIdx.x;                        // 768 blocks
  int swz = (flat & 7)*96 + (flat >> 3);        // XCD-contiguous chunks (768%8==0)
  int m0 = (swz / 48) * 128, n0 = (swz % 48) * 64;
  int lane = threadIdx.x & 63, wave = threadIdx.x >> 6;
  int wr = wave >> 1, wc = wave & 1, g = lane >> 4, c = lane & 15;
  int lrow = lane >> 3, scol = ((lane & 7) ^ lrow)*8;
  f4v acc[4][2] = {};
  stage12864(A, Bt, m0, n0, 0, As0, Bs0, wave, lrow, scol);
  __syncthreads();
  #pragma unroll 2
  for (int t=0; t<16; t++){
    const short* Ac = (t&1) ? As1 : As0;
    const short* Bc = (t&1) ? Bs1 : Bs0;
    short* An = (t&1) ? As0 : As1;
    short* Bn = (t&1) ? Bs0 : Bs1;
    if (t < 15) stage12864(A, Bt, m0, n0, (t+1)*64, An, Bn, wave, lrow, scol);
    comp12864(Ac, Bc, acc, wr, wc, g, c);
    __syncthreads();
  }

  int sec = n0 >> 10;                           // 0=Q 1=K 2=V (uniform)
  const float* bias = (sec==0) ? b_q : (sec==1) ? b_k : b_v;
  int b = m0 >> 10, s0 = m0 & 1023, h0 = (n0 & 1023) >> 6;
  #pragma unroll
  for (int mi=0;mi<4;mi++)
    #pragma unroll
    for (int ni=0;ni<2;ni++){
      int cl = wc*32 + ni*16 + c;               // 0..63 == d
      float bi = bias[(n0 & 1023) + cl];
      int ifr = cl >> 1;
      #pragma unroll
      for (int i=0;i<4;i++){
        int rl = wr*64 + mi*16 + g*4 + i;       // 0..127 local row
        float v = acc[mi][ni][i] + bi;
        if (sec < 2){
          int s = s0 + rl;
          float co = cs[s*32 + ifr], si = sn[s*32 + ifr];
          float p = __shfl_xor(v, 1, 64);       // partner col cl^1 (lane c^1), same row
          float o = (cl & 1) ? fmaf(p, si, v*co) : fmaf(v, co, -(p*si));
          if (sec == 0) o *= 0.125f;
          v = o;
        }
        st[rl*66 + cl] = f2bf(v);
      }
    }
  __syncthreads();
  if (sec < 2){
    short* dst = (sec==0) ? Qb : Kb;
    size_t base = ((size_t)(b*16+h0)*1024 + s0)*64;
    for (int e = threadIdx.x; e < 128*16; e += 256){
      int row = e >> 4, cl4 = (e & 15)*4;
      s4v o = *(const s4v*)(&st[row*66 + cl4]);
      *(s4v*)(&dst[base + (size_t)row*64 + cl4]) = o;
    }
  } else {
    size_t base = (size_t)(b*16+h0)*65536;
    for (int e = threadIdx.x; e < 64*32; e += 256){
      int d = e >> 5, s4 = (e & 31)*4;
      s4v o;
      o[0] = st[(s4+0)*66 + d]; o[1] = st[(s4+1)*66 + d];
      o[2] = st[(s4+2)*66 + d]; o[3] = st[(s4+3)*66 + d];
      *(s4v*)(&Vt[base + (size_t)d*1024 + s0 + s4]) = o;
    }
  }
}

// ---------------- out-proj GEMM (64x64, dbuf, 512 blocks = 2/CU): C f32 = A @ woT^T + b_o ----------------
__device__ __forceinline__ void stage6464(const short* __restrict__ A, const short* __restrict__ Bt,
                                          int m0, int n0, int k0, short* As, short* Bs,
                                          int wave, int lrow, int scol){
  #pragma unroll
  for (int p=0;p<2;p++){
    int r0 = wave*16 + p*8;
    gload16(A  + (size_t)(m0 + r0 + lrow)*1024 + k0 + scol, &As[r0*64]);
    gload16(Bt + (size_t)(n0 + r0 + lrow)*1024 + k0 + scol, &Bs[r0*64]);
  }
}
__global__ __launch_bounds__(256) void gemm_out_k(const short* __restrict__ A, const short* __restrict__ Bt,
                                                  const float* __restrict__ bias, float* __restrict__ C){
  __shared__ __align__(16) short As0[64*64];
  __shared__ __align__(16) short Bs0[64*64];
  __shared__ __align__(16) short As1[64*64];
  __shared__ __align__(16) short Bs1[64*64];
  int flat = blockIdx.x;                        // 512 blocks
  int swz = (flat & 7)*64 + (flat >> 3);
  int m0 = (swz >> 4)*64, n0 = (swz & 15)*64;
  int lane = threadIdx.x & 63, wave = threadIdx.x >> 6;
  int wr = wave >> 1, wc = wave & 1, g = lane >> 4, c = lane & 15;
  int lrow = lane >> 3, scol = ((lane & 7) ^ lrow)*8;
  f4v acc[2][2] = {};
  stage6464(A, Bt, m0, n0, 0, As0, Bs0, wave, lrow, scol);
  __syncthreads();
  #pragma unroll 2
  for (int t=0; t<16; t++){
    const short* Ac = (t&1) ? As1 : As0;
    const short* Bc = (t&1) ? Bs1 : Bs0;
    short* An = (t&1) ? As0 : As1;
    short* Bn = (t&1) ? Bs0 : Bs1;
    if (t < 15) stage6464(A, Bt, m0, n0, (t+1)*64, An, Bn, wave, lrow, scol);
    #pragma unroll
    for (int ks=0;ks<2;ks++){
      s8v a[2], b[2];
      int pu = ((ks*4 + g) ^ (c & 7))*8;
      #pragma unroll
      for (int mi=0;mi<2;mi++) a[mi] = *(const s8v*)(&Ac[(wr*32 + mi*16 + c)*64 + pu]);
      #pragma unroll
      for (int ni=0;ni<2;ni++) b[ni] = *(const s8v*)(&Bc[(wc*32 + ni*16 + c)*64 + pu]);
      #pragma unroll
      for (int mi=0;mi<2;mi++)
        #pragma unroll
        for (int ni=0;ni<2;ni++)
          acc[mi][ni] = __builtin_amdgcn_mfma_f32_16x16x32_bf16(a[mi], b[ni], acc[mi][ni], 0,0,0);
    }
    __syncthreads();
  }
  #pragma unroll
  for (int mi=0;mi<2;mi++)
    #pragma unroll
    for (int ni=0;ni<2;ni++){
      int col = n0 + wc*32 + ni*16 + c;
      float bi = bias[col];
      #pragma unroll
      for (int i=0;i<4;i++){
        int row = m0 + wr*32 + mi*16 + g*4 + i;
        C[(size_t)row*1024 + col] = acc[mi][ni][i] + bi;
      }
    }
}

// ---- fused attn (R12 core): S^T reg scores + windowed rel bias + theta-fold Newton x7 + PV; 0.25 folded ----
#define ATPAD 1028
__global__ __launch_bounds__(256,4) void attn_fused_k(const short* __restrict__ Qb, const short* __restrict__ Kb,
                                                      const short* __restrict__ relb, const short* __restrict__ relT,
                                                      const short* __restrict__ Vt, short* __restrict__ ctxb){
  __shared__ __align__(16) short pb_b[16][66];       // q.rel^T bf16; later aliased as reduce scratch
  __shared__ __align__(16) float wrow[16][68];       // in-window bucket weights f32 (j=1..63), UNscaled (4x)
  __shared__ __align__(16) short attn_l[16][ATPAD];  // attn' = (x-theta)_+^2 bf16 (4x attn)
  float2* red = (float2*)&pb_b[0][0];

  int lane = threadIdx.x & 63, wave = threadIdx.x >> 6;
  int g = lane >> 4, c = lane & 15;
  int flat = blockIdx.x;                              // 2048
  int swz = (flat & 7)*256 + (flat >> 3);
  int bh = swz >> 6, q0 = (swz & 63)*16;
  const short* Qh = Qb + (size_t)bh*65536;
  const short* Kh = Kb + (size_t)bh*65536;
  const short* Vh = Vt + (size_t)bh*65536;

  for (int e = threadIdx.x; e < 16*68; e += 256) ((float*)wrow)[e] = 0.f;

  s8v qa0 = *(const s8v*)(Qh + (q0+c)*64 + g*8);
  s8v qa1 = *(const s8v*)(Qh + (q0+c)*64 + 32 + g*8);

  // pb[r][j] = q_row(r) . rel_emb[j] via MFMA
  {
    int ntile = (wave==3) ? 2 : 1;
    for (int t=0; t<ntile; t++){
      int jt = (t==0) ? wave : 4;
      int j = jt*16 + c;
      s8v rb0 = {}, rb1 = {};
      if (j < 65){
        rb0 = *(const s8v*)(relb + j*64 + g*8);
        rb1 = *(const s8v*)(relb + j*64 + 32 + g*8);
      }
      f4v pa = {};
      pa = __builtin_amdgcn_mfma_f32_16x16x32_bf16(qa0, rb0, pa, 0,0,0);
      pa = __builtin_amdgcn_mfma_f32_16x16x32_bf16(qa1, rb1, pa, 0,0,0);
      if (j < 65){
        #pragma unroll
        for (int i=0;i<4;i++) pb_b[g*4+i][j] = f2bf(pa[i]);
      }
    }
  }
  __syncthreads();

  // scores^T: lane (g,c) holds S[q0+c][k], k = kc0 + t*16 + g*4 + i; windowed pb as C-init
  int q = q0 + c;
  int kc0 = wave*256;
  int Lb = q0 - 32 - kc0;
  int Ub = q0 + 47 - kc0;
  float pb0  = bf2f(pb_b[c][0]);
  float pb64 = bf2f(pb_b[c][64]);
  f4v x[16];
  __builtin_amdgcn_s_setprio(1);
  #pragma unroll
  for (int t=0;t<16;t++){
    f4v ini;
    if (t*16+15 <= Lb){ ini[0]=pb0; ini[1]=pb0; ini[2]=pb0; ini[3]=pb0; }
    else if (t*16 >= Ub){ ini[0]=pb64; ini[1]=pb64; ini[2]=pb64; ini[3]=pb64; }
    else {
      #pragma unroll
      for (int i=0;i<4;i++){
        int k = kc0 + t*16 + g*4 + i;
        int jj = min(max(k - q, -32), 32) + 32;
        ini[i] = bf2f(pb_b[c][jj]);
      }
    }
    const short* kp = Kh + (kc0 + t*16 + c)*64 + g*8;
    s8v ka0 = *(const s8v*)(kp);
    s8v ka1 = *(const s8v*)(kp + 32);
    ini = __builtin_amdgcn_mfma_f32_16x16x32_bf16(ka0, qa0, ini, 0,0,0);
    x[t] = __builtin_amdgcn_mfma_f32_16x16x32_bf16(ka1, qa1, ini, 0,0,0);
  }
  __builtin_amdgcn_s_setprio(0);

  // V prefetch: first 8 PV tiles into registers (latency hides under max+Newton)
  s8v vf[8];
  #pragma unroll
  for (int kk=0;kk<8;kk++)
    vf[kk] = *(const s8v*)(Vh + (size_t)(wave*16+c)*1024 + kk*32 + g*8);

  __syncthreads();   // pb_b dead; red alias safe

  // row max
  f4v m4 = x[0];
  #pragma unroll
  for (int t=1;t<16;t++){
    m4[0]=fmaxf(m4[0],x[t][0]); m4[1]=fmaxf(m4[1],x[t][1]);
    m4[2]=fmaxf(m4[2],x[t][2]); m4[3]=fmaxf(m4[3],x[t][3]);
  }
  float mx = fmaxf(fmaxf(m4[0],m4[1]), fmaxf(m4[2],m4[3]));
  mx = fmaxf(mx, __shfl_xor(mx, 16, 64));
  mx = fmaxf(mx, __shfl_xor(mx, 32, 64));
  if (g == 0) red[wave*16 + c] = make_float2(mx, 0.f);
  __syncthreads();
  {
    float2 r0 = red[c], r1 = red[16+c], r2 = red[32+c], r3 = red[48+c];
    mx = fmaxf(fmaxf(r0.x, r1.x), fmaxf(r2.x, r3.x));
  }

  // theta-fold Newton x7 (packed f32 math): theta = mx + 2*tau
  // it=0..6: pp=(it+1)&1 = 1,0,1,0,1,0,1 -> last uses slots 64..127; bucket partials go to 0..63
  float theta = mx - 2.0f;
  for (int it=0; it<7; it++){
    f4v th4 = {theta, theta, theta, theta};
    f4v s1v = {0.f,0.f,0.f,0.f}, s2v = {0.f,0.f,0.f,0.f};
    #pragma unroll
    for (int t=0;t<16;t++){
      f4v d = x[t] - th4;
      f4v tt;
      tt[0]=fmaxf(d[0],0.f); tt[1]=fmaxf(d[1],0.f); tt[2]=fmaxf(d[2],0.f); tt[3]=fmaxf(d[3],0.f);
      s1v += tt;
      s2v += tt*tt;
    }
    float S1 = (s1v[0]+s1v[1])+(s1v[2]+s1v[3]);
    float S2 = (s2v[0]+s2v[1])+(s2v[2]+s2v[3]);
    S1 += __shfl_xor(S1, 16, 64); S2 += __shfl_xor(S2, 16, 64);
    S1 += __shfl_xor(S1, 32, 64); S2 += __shfl_xor(S2, 32, 64);
    int pp = (it+1)&1;
    if (g == 0) red[(pp*4 + wave)*16 + c] = make_float2(S1, S2);
    __syncthreads();
    float2 r0 = red[pp*64 + c], r1 = red[pp*64 + 16+c], r2 = red[pp*64 + 32+c], r3 = red[pp*64 + 48+c];
    S1 = (r0.x+r1.x)+(r2.x+r3.x);
    S2 = (r0.y+r1.y)+(r2.y+r3.y);
    theta += (S2 - 4.0f)/(2.0f*S1);
  }

  // epilogue: attn' = (x-theta)_+^2 (4x attn; scale folded into final store) -> LDS; windowed buckets
  float w0p = 0.f, w64p = 0.f;
  {
    f4v th4 = {theta, theta, theta, theta};
    short* arow = &attn_l[c][kc0 + g*4];
    #pragma unroll
    for (int t=0;t<16;t++){
      f4v d = x[t] - th4;
      f4v tt;
      tt[0]=fmaxf(d[0],0.f); tt[1]=fmaxf(d[1],0.f); tt[2]=fmaxf(d[2],0.f); tt[3]=fmaxf(d[3],0.f);
      f4v a = tt*tt;
      unsigned d0, d1;
      asm("v_cvt_pk_bf16_f32 %0, %1, %2" : "=v"(d0) : "v"(a[0]), "v"(a[1]));
      asm("v_cvt_pk_bf16_f32 %0, %1, %2" : "=v"(d1) : "v"(a[2]), "v"(a[3]));
      *(uint2*)(arow + t*16) = make_uint2(d0, d1);
      if (t*16+15 <= Lb)      w0p  += (a[0]+a[1])+(a[2]+a[3]);
      else if (t*16 >= Ub)    w64p += (a[0]+a[1])+(a[2]+a[3]);
      else {
        #pragma unroll
        for (int i=0;i<4;i++){
          int raw = kc0 + t*16 + g*4 + i - q;
          if (raw <= -32) w0p += a[i];
          else if (raw >= 32) w64p += a[i];
          else wrow[c][raw+32] = a[i];   // raw+32 in 1..63: slot 0 stays zero
        }
      }
    }
  }
  w0p += __shfl_xor(w0p, 16, 64); w64p += __shfl_xor(w64p, 16, 64);
  w0p += __shfl_xor(w0p, 32, 64); w64p += __shfl_xor(w64p, 32, 64);
  if (g == 0) red[wave*16 + c] = make_float2(w0p, w64p);   // slots 0..63 (last Newton used 64..127)
  __syncthreads();                                         // B6: wrow+attn_l+red ready

  // PV: wave owns d-cols [wave*16,+16), full K=1024; first 8 tiles from vf regs; dual accumulator
  f4v acc0 = {}, acc1 = {};
  __builtin_amdgcn_s_setprio(1);
  #pragma unroll
  for (int kk=0; kk<8; kk+=2){
    s8v af0 = *(const s8v*)(&attn_l[c][kk*32 + g*8]);
    acc0 = __builtin_amdgcn_mfma_f32_16x16x32_bf16(af0, vf[kk], acc0, 0,0,0);
    s8v af1 = *(const s8v*)(&attn_l[c][(kk+1)*32 + g*8]);
    acc1 = __builtin_amdgcn_mfma_f32_16x16x32_bf16(af1, vf[kk+1], acc1, 0,0,0);
  }
  #pragma unroll
  for (int kk=8; kk<32; kk+=2){
    s8v af0 = *(const s8v*)(&attn_l[c][kk*32 + g*8]);
    s8v bf0 = *(const s8v*)(Vh + (size_t)(wave*16+c)*1024 + kk*32 + g*8);
    acc0 = __builtin_amdgcn_mfma_f32_16x16x32_bf16(af0, bf0, acc0, 0,0,0);
    s8v af1 = *(const s8v*)(&attn_l[c][(kk+1)*32 + g*8]);
    s8v bf1 = *(const s8v*)(Vh + (size_t)(wave*16+c)*1024 + (kk+1)*32 + g*8);
    acc1 = __builtin_amdgcn_mfma_f32_16x16x32_bf16(af1, bf1, acc1, 0,0,0);
  }
  f4v acc = acc0 + acc1;
  {
    const float* wp = &wrow[c][0];
    f4v A0 = *(const f4v*)(wp + g*8);
    f4v A1 = *(const f4v*)(wp + g*8 + 4);
    f4v A2 = *(const f4v*)(wp + 32 + g*8);
    f4v A3 = *(const f4v*)(wp + 32 + g*8 + 4);
    union { unsigned u[4]; s8v v; } W0, W1;
    asm("v_cvt_pk_bf16_f32 %0, %1, %2" : "=v"(W0.u[0]) : "v"(A0[0]), "v"(A0[1]));
    asm("v_cvt_pk_bf16_f32 %0, %1, %2" : "=v"(W0.u[1]) : "v"(A0[2]), "v"(A0[3]));
    asm("v_cvt_pk_bf16_f32 %0, %1, %2" : "=v"(W0.u[2]) : "v"(A1[0]), "v"(A1[1]));
    asm("v_cvt_pk_bf16_f32 %0, %1, %2" : "=v"(W0.u[3]) : "v"(A1[2]), "v"(A1[3]));
    asm("v_cvt_pk_bf16_f32 %0, %1, %2" : "=v"(W1.u[0]) : "v"(A2[0]), "v"(A2[1]));
    asm("v_cvt_pk_bf16_f32 %0, %1, %2" : "=v"(W1.u[1]) : "v"(A2[2]), "v"(A2[3]));
    asm("v_cvt_pk_bf16_f32 %0, %1, %2" : "=v"(W1.u[2]) : "v"(A3[0]), "v"(A3[1]));
    asm("v_cvt_pk_bf16_f32 %0, %1, %2" : "=v"(W1.u[3]) : "v"(A3[2]), "v"(A3[3]));
    s8v rb0 = *(const s8v*)(relT + (wave*16+c)*72 + g*8);
    s8v rb1 = *(const s8v*)(relT + (wave*16+c)*72 + 32 + g*8);
    acc = __builtin_amdgcn_mfma_f32_16x16x32_bf16(W0.v, rb0, acc, 0,0,0);
    acc = __builtin_amdgcn_mfma_f32_16x16x32_bf16(W1.v, rb1, acc, 0,0,0);
  }
  __builtin_amdgcn_s_setprio(0);

  // store: add j=0 and j=64 bucket terms, apply global 0.25 scale (undoes the 4x attn')
  int b = bh >> 4, h = bh & 15, d = wave*16 + c;
  float rl0  = bf2f(relT[d*72 + 0]);
  float rl64 = bf2f(relT[d*72 + 64]);
  #pragma unroll
  for (int i=0;i<4;i++){
    int r = g*4+i;
    float2 p0 = red[r], p1 = red[16+r], p2 = red[32+r], p3 = red[48+r];
    float w0 = (p0.x+p1.x)+(p2.x+p3.x);
    float w64v = (p0.y+p1.y)+(p2.y+p3.y);
    float s = 0.25f*(acc[i] + w0*rl0 + w64v*rl64);
    ctxb[((size_t)(b*1024 + q0 + r))*1024 + h*64 + d] = f2bf(s);
  }
}

extern "C" void kernel_launch(void* const* d_in, const int* in_sizes, int n_in,
                              void* d_out, int out_size, void* d_ws, size_t ws_size,
                              hipStream_t stream) {
  (void)in_sizes; (void)n_in; (void)out_size; (void)ws_size;
  const float* x    = (const float*)d_in[0];
  const float* w_q  = (const float*)d_in[1];
  const float* b_q  = (const float*)d_in[2];
  const float* w_k  = (const float*)d_in[3];
  const float* b_k  = (const float*)d_in[4];
  const float* w_v  = (const float*)d_in[5];
  const float* b_v  = (const float*)d_in[6];
  const float* w_o  = (const float*)d_in[7];
  const float* b_o  = (const float*)d_in[8];
  const float* rel  = (const float*)d_in[9];
  const float* rcos = (const float*)d_in[10];
  const float* rsin = (const float*)d_in[11];
  float* out = (float*)d_out;

  char* w = (char*)d_ws;
  short* xb    = (short*)(w);                        // 4 MiB
  short* wqkvT = (short*)(w + ((size_t)4<<20));      // 6 MiB  [3072][1024]
  short* woT   = (short*)(w + ((size_t)10<<20));     // 2 MiB
  short* Qb    = (short*)(w + ((size_t)12<<20));     // 4 MiB
  short* Kb    = (short*)(w + ((size_t)16<<20));     // 4 MiB
  short* Vt    = (short*)(w + ((size_t)20<<20));     // 4 MiB
  short* ctxb  = (short*)(w + ((size_t)24<<20));     // 4 MiB
  short* relb  = (short*)(w + ((size_t)28<<20));     // 8.3 KB
  short* relT  = (short*)(w + ((size_t)28<<20) + 65536); // 9.2 KB

  prep_k<<<dim3(16,16,6), 256, 0, stream>>>(w_q, w_k, w_v, w_o, x, rel, wqkvT, woT, xb, relb, relT);
  gemm_qkv_k<<<768, 256, 0, stream>>>(xb, wqkvT, b_q, b_k, b_v, rcos, rsin, Qb, Kb, Vt);
  attn_fused_k<<<2048, 256, 0, stream>>>(Qb, Kb, relb, relT, Vt, ctxb);
  gemm_out_k<<<512, 256, 0, stream>>>(ctxb, woT, b_o, out);
}

// Round 15
// 119.691 us; speedup vs baseline: 1.3687x; 1.0089x over previous
//
#include <hip/hip_runtime.h>

typedef __attribute__((ext_vector_type(8))) short s8v;
typedef __attribute__((ext_vector_type(4))) short s4v;
typedef __attribute__((ext_vector_type(4))) float f4v;

__device__ __forceinline__ short f2bf(float f){
  union { float f; unsigned u; } v; v.f = f;
  unsigned r = v.u + 0x7fffu + ((v.u >> 16) & 1u);
  return (short)(r >> 16);
}
__device__ __forceinline__ float bf2f(short s){
  union { unsigned u; float f; } v; v.u = ((unsigned)(unsigned short)s) << 16; return v.f;
}
__device__ __forceinline__ void gload16(const void* g, void* l){
  __builtin_amdgcn_global_load_lds((const __attribute__((address_space(1))) unsigned int*)g,
                                   (__attribute__((address_space(3))) unsigned int*)l, 16, 0, 0);
}

// ---------------- unified prep: 4 W-transposes (z=0..3), x->bf16 (z=4..5), rel prep (block 0,0,3) ----------------
__global__ __launch_bounds__(256) void prep_k(const float* __restrict__ w_q, const float* __restrict__ w_k,
                                              const float* __restrict__ w_v, const float* __restrict__ w_o,
                                              const float* __restrict__ x, const float* __restrict__ rel,
                                              short* __restrict__ wqkvT, short* __restrict__ woT,
                                              short* __restrict__ xb, short* __restrict__ relb,
                                              short* __restrict__ relT){
  int z = blockIdx.z;
  if (z < 4){
    __shared__ float t[64][65];
    const float* in = (z==0) ? w_q : (z==1) ? w_k : (z==2) ? w_v : w_o;
    short* out = (z==3) ? woT : (wqkvT + ((size_t)z<<20));
    int c0 = blockIdx.x*64, r0 = blockIdx.y*64;
    int tx = threadIdx.x & 63, ty = threadIdx.x >> 6;
    #pragma unroll
    for (int i=0;i<16;i++){ int r = ty + i*4; t[r][tx] = in[(size_t)(r0+r)*1024 + c0+tx]; }
    __syncthreads();
    #pragma unroll
    for (int i=0;i<16;i++){ int cc = ty + i*4; out[(size_t)(c0+cc)*1024 + r0+tx] = f2bf(t[tx][cc]); }
    if (z==3 && blockIdx.x==0 && blockIdx.y==0){
      for (int e = threadIdx.x; e < 65*64; e += 256){
        int j = e >> 6, d = e & 63;
        short bv = f2bf(rel[e]);
        relb[e] = bv;
        relT[d*72 + j] = bv;
      }
    }
  } else {
    int bid = (z-4)*256 + blockIdx.y*16 + blockIdx.x;
    int i = bid*256 + threadIdx.x;
    #pragma unroll
    for (int p=0;p<4;p++){
      int idx = p*131072 + i;
      f4v v = ((const f4v*)x)[idx];
      s4v o; o[0]=f2bf(v[0]); o[1]=f2bf(v[1]); o[2]=f2bf(v[2]); o[3]=f2bf(v[3]);
      ((s4v*)xb)[idx] = o;
    }
  }
}

// ---- 128x64 GEMM pieces: source-swizzled gload16 staging + XOR'd frag read; counted-vmcnt dbuf loop ----
__device__ __forceinline__ void stage12864(const short* __restrict__ A, const short* __restrict__ Bt,
                                           int m0, int n0, int k0, short* As, short* Bs,
                                           int wave, int lrow, int scol){
  #pragma unroll
  for (int p=0;p<4;p++){
    int r0 = wave*32 + p*8;
    gload16(A + (size_t)(m0 + r0 + lrow)*1024 + k0 + scol, &As[r0*64]);
  }
  #pragma unroll
  for (int p=0;p<2;p++){
    int r0 = wave*16 + p*8;
    gload16(Bt + (size_t)(n0 + r0 + lrow)*1024 + k0 + scol, &Bs[r0*64]);
  }
}
__device__ __forceinline__ void comp12864(const short* As, const short* Bs, f4v acc[4][2],
                                          int wr, int wc, int g, int c){
  #pragma unroll
  for (int ks=0;ks<2;ks++){
    s8v a[4], b[2];
    int pu = ((ks*4 + g) ^ (c & 7))*8;
    #pragma unroll
    for (int mi=0;mi<4;mi++) a[mi] = *(const s8v*)(&As[(wr*64 + mi*16 + c)*64 + pu]);
    #pragma unroll
    for (int ni=0;ni<2;ni++) b[ni] = *(const s8v*)(&Bs[(wc*32 + ni*16 + c)*64 + pu]);
    #pragma unroll
    for (int mi=0;mi<4;mi++)
      #pragma unroll
      for (int ni=0;ni<2;ni++)
        acc[mi][ni] = __builtin_amdgcn_mfma_f32_16x16x32_bf16(a[mi], b[ni], acc[mi][ni], 0,0,0);
  }
}

// ---------------- fused QKV GEMM (128x64, counted-vmcnt dbuf): bias + RoPE + layouts ----------------
__global__ __launch_bounds__(256) void gemm_qkv_k(const short* __restrict__ A, const short* __restrict__ Bt,
                                                  const float* __restrict__ b_q, const float* __restrict__ b_k,
                                                  const float* __restrict__ b_v,
                                                  const float* __restrict__ cs, const float* __restrict__ sn,
                                                  short* __restrict__ Qb, short* __restrict__ Kb,
                                                  short* __restrict__ Vt){
  __shared__ __align__(16) char lbuf[49152];    // 2x(16KB A + 8KB B); epilogue st[128][66] (16896B) reuses
  short* As0 = (short*)lbuf;
  short* Bs0 = (short*)(lbuf + 16384);
  short* As1 = (short*)(lbuf + 24576);
  short* Bs1 = (short*)(lbuf + 40960);
  short* st  = (short*)lbuf;
  int flat = blockIdx.x;                        // 768 blocks
  int swz = (flat & 7)*96 + (flat >> 3);        // XCD-contiguous chunks (768%8==0)
  int m0 = (swz / 48) * 128, n0 = (swz % 48) * 64;
  int lane = threadIdx.x & 63, wave = threadIdx.x >> 6;
  int wr = wave >> 1, wc = wave & 1, g = lane >> 4, c = lane & 15;
  int lrow = lane >> 3, scol = ((lane & 7) ^ lrow)*8;
  f4v acc[4][2] = {};
  stage12864(A, Bt, m0, n0, 0, As0, Bs0, wave, lrow, scol);
  #pragma unroll 2
  for (int t=0; t<16; t++){
    const short* Ac = (t&1) ? As1 : As0;
    const short* Bc = (t&1) ? Bs1 : Bs0;
    short* An = (t&1) ? As0 : As1;
    short* Bn = (t&1) ? Bs0 : Bs1;
    if (t < 15){
      stage12864(A, Bt, m0, n0, (t+1)*64, An, Bn, wave, lrow, scol);
      asm volatile("s_waitcnt vmcnt(6)" ::: "memory");   // prev tile's 6 loads done; 6 new in flight
    } else {
      asm volatile("s_waitcnt vmcnt(0)" ::: "memory");
    }
    __builtin_amdgcn_sched_barrier(0);
    __builtin_amdgcn_s_barrier();                         // all waves' cur-tile loads landed
    __builtin_amdgcn_sched_barrier(0);
    comp12864(Ac, Bc, acc, wr, wc, g, c);
    __builtin_amdgcn_sched_barrier(0);
    __builtin_amdgcn_s_barrier();                         // all waves done reading cur before overwrite
    __builtin_amdgcn_sched_barrier(0);
  }

  int sec = n0 >> 10;                           // 0=Q 1=K 2=V (uniform)
  const float* bias = (sec==0) ? b_q : (sec==1) ? b_k : b_v;
  int b = m0 >> 10, s0 = m0 & 1023, h0 = (n0 & 1023) >> 6;
  #pragma unroll
  for (int mi=0;mi<4;mi++)
    #pragma unroll
    for (int ni=0;ni<2;ni++){
      int cl = wc*32 + ni*16 + c;               // 0..63 == d
      float bi = bias[(n0 & 1023) + cl];
      int ifr = cl >> 1;
      #pragma unroll
      for (int i=0;i<4;i++){
        int rl = wr*64 + mi*16 + g*4 + i;       // 0..127 local row
        float v = acc[mi][ni][i] + bi;
        if (sec < 2){
          int s = s0 + rl;
          float co = cs[s*32 + ifr], si = sn[s*32 + ifr];
          float p = __shfl_xor(v, 1, 64);       // partner col cl^1 (lane c^1), same row
          float o = (cl & 1) ? fmaf(p, si, v*co) : fmaf(v, co, -(p*si));
          if (sec == 0) o *= 0.125f;
          v = o;
        }
        st[rl*66 + cl] = f2bf(v);
      }
    }
  __syncthreads();
  if (sec < 2){
    short* dst = (sec==0) ? Qb : Kb;
    size_t base = ((size_t)(b*16+h0)*1024 + s0)*64;
    for (int e = threadIdx.x; e < 128*16; e += 256){
      int row = e >> 4, cl4 = (e & 15)*4;
      s4v o = *(const s4v*)(&st[row*66 + cl4]);
      *(s4v*)(&dst[base + (size_t)row*64 + cl4]) = o;
    }
  } else {
    size_t base = (size_t)(b*16+h0)*65536;
    for (int e = threadIdx.x; e < 64*32; e += 256){
      int d = e >> 5, s4 = (e & 31)*4;
      s4v o;
      o[0] = st[(s4+0)*66 + d]; o[1] = st[(s4+1)*66 + d];
      o[2] = st[(s4+2)*66 + d]; o[3] = st[(s4+3)*66 + d];
      *(s4v*)(&Vt[base + (size_t)d*1024 + s0 + s4]) = o;
    }
  }
}

// ---------------- out-proj GEMM (64x64, counted-vmcnt dbuf, 512 blocks): C f32 = A @ woT^T + b_o ----------------
__device__ __forceinline__ void stage6464(const short* __restrict__ A, const short* __restrict__ Bt,
                                          int m0, int n0, int k0, short* As, short* Bs,
                                          int wave, int lrow, int scol){
  #pragma unroll
  for (int p=0;p<2;p++){
    int r0 = wave*16 + p*8;
    gload16(A  + (size_t)(m0 + r0 + lrow)*1024 + k0 + scol, &As[r0*64]);
    gload16(Bt + (size_t)(n0 + r0 + lrow)*1024 + k0 + scol, &Bs[r0*64]);
  }
}
__global__ __launch_bounds__(256) void gemm_out_k(const short* __restrict__ A, const short* __restrict__ Bt,
                                                  const float* __restrict__ bias, float* __restrict__ C){
  __shared__ __align__(16) short As0[64*64];
  __shared__ __align__(16) short Bs0[64*64];
  __shared__ __align__(16) short As1[64*64];
  __shared__ __align__(16) short Bs1[64*64];
  int flat = blockIdx.x;                        // 512 blocks
  int swz = (flat & 7)*64 + (flat >> 3);
  int m0 = (swz >> 4)*64, n0 = (swz & 15)*64;
  int lane = threadIdx.x & 63, wave = threadIdx.x >> 6;
  int wr = wave >> 1, wc = wave & 1, g = lane >> 4, c = lane & 15;
  int lrow = lane >> 3, scol = ((lane & 7) ^ lrow)*8;
  f4v acc[2][2] = {};
  stage6464(A, Bt, m0, n0, 0, As0, Bs0, wave, lrow, scol);
  #pragma unroll 2
  for (int t=0; t<16; t++){
    const short* Ac = (t&1) ? As1 : As0;
    const short* Bc = (t&1) ? Bs1 : Bs0;
    short* An = (t&1) ? As0 : As1;
    short* Bn = (t&1) ? Bs0 : Bs1;
    if (t < 15){
      stage6464(A, Bt, m0, n0, (t+1)*64, An, Bn, wave, lrow, scol);
      asm volatile("s_waitcnt vmcnt(4)" ::: "memory");   // prev tile's 4 loads done; 4 new in flight
    } else {
      asm volatile("s_waitcnt vmcnt(0)" ::: "memory");
    }
    __builtin_amdgcn_sched_barrier(0);
    __builtin_amdgcn_s_barrier();
    __builtin_amdgcn_sched_barrier(0);
    #pragma unroll
    for (int ks=0;ks<2;ks++){
      s8v a[2], b[2];
      int pu = ((ks*4 + g) ^ (c & 7))*8;
      #pragma unroll
      for (int mi=0;mi<2;mi++) a[mi] = *(const s8v*)(&Ac[(wr*32 + mi*16 + c)*64 + pu]);
      #pragma unroll
      for (int ni=0;ni<2;ni++) b[ni] = *(const s8v*)(&Bc[(wc*32 + ni*16 + c)*64 + pu]);
      #pragma unroll
      for (int mi=0;mi<2;mi++)
        #pragma unroll
        for (int ni=0;ni<2;ni++)
          acc[mi][ni] = __builtin_amdgcn_mfma_f32_16x16x32_bf16(a[mi], b[ni], acc[mi][ni], 0,0,0);
    }
    __builtin_amdgcn_sched_barrier(0);
    __builtin_amdgcn_s_barrier();
    __builtin_amdgcn_sched_barrier(0);
  }
  #pragma unroll
  for (int mi=0;mi<2;mi++)
    #pragma unroll
    for (int ni=0;ni<2;ni++){
      int col = n0 + wc*32 + ni*16 + c;
      float bi = bias[col];
      #pragma unroll
      for (int i=0;i<4;i++){
        int row = m0 + wr*32 + mi*16 + g*4 + i;
        C[(size_t)row*1024 + col] = acc[mi][ni][i] + bi;
      }
    }
}

// ---- fused attn (R14, unchanged): S^T reg scores + windowed rel bias + theta-fold Newton x7 + PV; 0.25 folded ----
#define ATPAD 1028
__global__ __launch_bounds__(256,4) void attn_fused_k(const short* __restrict__ Qb, const short* __restrict__ Kb,
                                                      const short* __restrict__ relb, const short* __restrict__ relT,
                                                      const short* __restrict__ Vt, short* __restrict__ ctxb){
  __shared__ __align__(16) short pb_b[16][66];       // q.rel^T bf16; later aliased as reduce scratch
  __shared__ __align__(16) float wrow[16][68];       // in-window bucket weights f32 (j=1..63), UNscaled (4x)
  __shared__ __align__(16) short attn_l[16][ATPAD];  // attn' = (x-theta)_+^2 bf16 (4x attn)
  float2* red = (float2*)&pb_b[0][0];

  int lane = threadIdx.x & 63, wave = threadIdx.x >> 6;
  int g = lane >> 4, c = lane & 15;
  int flat = blockIdx.x;                              // 2048
  int swz = (flat & 7)*256 + (flat >> 3);
  int bh = swz >> 6, q0 = (swz & 63)*16;
  const short* Qh = Qb + (size_t)bh*65536;
  const short* Kh = Kb + (size_t)bh*65536;
  const short* Vh = Vt + (size_t)bh*65536;

  for (int e = threadIdx.x; e < 16*68; e += 256) ((float*)wrow)[e] = 0.f;

  s8v qa0 = *(const s8v*)(Qh + (q0+c)*64 + g*8);
  s8v qa1 = *(const s8v*)(Qh + (q0+c)*64 + 32 + g*8);

  // pb[r][j] = q_row(r) . rel_emb[j] via MFMA
  {
    int ntile = (wave==3) ? 2 : 1;
    for (int t=0; t<ntile; t++){
      int jt = (t==0) ? wave : 4;
      int j = jt*16 + c;
      s8v rb0 = {}, rb1 = {};
      if (j < 65){
        rb0 = *(const s8v*)(relb + j*64 + g*8);
        rb1 = *(const s8v*)(relb + j*64 + 32 + g*8);
      }
      f4v pa = {};
      pa = __builtin_amdgcn_mfma_f32_16x16x32_bf16(qa0, rb0, pa, 0,0,0);
      pa = __builtin_amdgcn_mfma_f32_16x16x32_bf16(qa1, rb1, pa, 0,0,0);
      if (j < 65){
        #pragma unroll
        for (int i=0;i<4;i++) pb_b[g*4+i][j] = f2bf(pa[i]);
      }
    }
  }
  __syncthreads();

  // scores^T: lane (g,c) holds S[q0+c][k], k = kc0 + t*16 + g*4 + i; windowed pb as C-init
  int q = q0 + c;
  int kc0 = wave*256;
  int Lb = q0 - 32 - kc0;
  int Ub = q0 + 47 - kc0;
  float pb0  = bf2f(pb_b[c][0]);
  float pb64 = bf2f(pb_b[c][64]);
  f4v x[16];
  __builtin_amdgcn_s_setprio(1);
  #pragma unroll
  for (int t=0;t<16;t++){
    f4v ini;
    if (t*16+15 <= Lb){ ini[0]=pb0; ini[1]=pb0; ini[2]=pb0; ini[3]=pb0; }
    else if (t*16 >= Ub){ ini[0]=pb64; ini[1]=pb64; ini[2]=pb64; ini[3]=pb64; }
    else {
      #pragma unroll
      for (int i=0;i<4;i++){
        int k = kc0 + t*16 + g*4 + i;
        int jj = min(max(k - q, -32), 32) + 32;
        ini[i] = bf2f(pb_b[c][jj]);
      }
    }
    const short* kp = Kh + (kc0 + t*16 + c)*64 + g*8;
    s8v ka0 = *(const s8v*)(kp);
    s8v ka1 = *(const s8v*)(kp + 32);
    ini = __builtin_amdgcn_mfma_f32_16x16x32_bf16(ka0, qa0, ini, 0,0,0);
    x[t] = __builtin_amdgcn_mfma_f32_16x16x32_bf16(ka1, qa1, ini, 0,0,0);
  }
  __builtin_amdgcn_s_setprio(0);

  // V prefetch: first 8 PV tiles into registers (latency hides under max+Newton)
  s8v vf[8];
  #pragma unroll
  for (int kk=0;kk<8;kk++)
    vf[kk] = *(const s8v*)(Vh + (size_t)(wave*16+c)*1024 + kk*32 + g*8);

  __syncthreads();   // pb_b dead; red alias safe

  // row max
  f4v m4 = x[0];
  #pragma unroll
  for (int t=1;t<16;t++){
    m4[0]=fmaxf(m4[0],x[t][0]); m4[1]=fmaxf(m4[1],x[t][1]);
    m4[2]=fmaxf(m4[2],x[t][2]); m4[3]=fmaxf(m4[3],x[t][3]);
  }
  float mx = fmaxf(fmaxf(m4[0],m4[1]), fmaxf(m4[2],m4[3]));
  mx = fmaxf(mx, __shfl_xor(mx, 16, 64));
  mx = fmaxf(mx, __shfl_xor(mx, 32, 64));
  if (g == 0) red[wave*16 + c] = make_float2(mx, 0.f);
  __syncthreads();
  {
    float2 r0 = red[c], r1 = red[16+c], r2 = red[32+c], r3 = red[48+c];
    mx = fmaxf(fmaxf(r0.x, r1.x), fmaxf(r2.x, r3.x));
  }

  // theta-fold Newton x7 (packed f32 math): theta = mx + 2*tau
  // it=0..6: pp=(it+1)&1 = 1,0,1,0,1,0,1 -> last uses slots 64..127; bucket partials go to 0..63
  float theta = mx - 2.0f;
  for (int it=0; it<7; it++){
    f4v th4 = {theta, theta, theta, theta};
    f4v s1v = {0.f,0.f,0.f,0.f}, s2v = {0.f,0.f,0.f,0.f};
    #pragma unroll
    for (int t=0;t<16;t++){
      f4v d = x[t] - th4;
      f4v tt;
      tt[0]=fmaxf(d[0],0.f); tt[1]=fmaxf(d[1],0.f); tt[2]=fmaxf(d[2],0.f); tt[3]=fmaxf(d[3],0.f);
      s1v += tt;
      s2v += tt*tt;
    }
    float S1 = (s1v[0]+s1v[1])+(s1v[2]+s1v[3]);
    float S2 = (s2v[0]+s2v[1])+(s2v[2]+s2v[3]);
    S1 += __shfl_xor(S1, 16, 64); S2 += __shfl_xor(S2, 16, 64);
    S1 += __shfl_xor(S1, 32, 64); S2 += __shfl_xor(S2, 32, 64);
    int pp = (it+1)&1;
    if (g == 0) red[(pp*4 + wave)*16 + c] = make_float2(S1, S2);
    __syncthreads();
    float2 r0 = red[pp*64 + c], r1 = red[pp*64 + 16+c], r2 = red[pp*64 + 32+c], r3 = red[pp*64 + 48+c];
    S1 = (r0.x+r1.x)+(r2.x+r3.x);
    S2 = (r0.y+r1.y)+(r2.y+r3.y);
    theta += (S2 - 4.0f)/(2.0f*S1);
  }

  // epilogue: attn' = (x-theta)_+^2 (4x attn; scale folded into final store) -> LDS; windowed buckets
  float w0p = 0.f, w64p = 0.f;
  {
    f4v th4 = {theta, theta, theta, theta};
    short* arow = &attn_l[c][kc0 + g*4];
    #pragma unroll
    for (int t=0;t<16;t++){
      f4v d = x[t] - th4;
      f4v tt;
      tt[0]=fmaxf(d[0],0.f); tt[1]=fmaxf(d[1],0.f); tt[2]=fmaxf(d[2],0.f); tt[3]=fmaxf(d[3],0.f);
      f4v a = tt*tt;
      unsigned d0, d1;
      asm("v_cvt_pk_bf16_f32 %0, %1, %2" : "=v"(d0) : "v"(a[0]), "v"(a[1]));
      asm("v_cvt_pk_bf16_f32 %0, %1, %2" : "=v"(d1) : "v"(a[2]), "v"(a[3]));
      *(uint2*)(arow + t*16) = make_uint2(d0, d1);
      if (t*16+15 <= Lb)      w0p  += (a[0]+a[1])+(a[2]+a[3]);
      else if (t*16 >= Ub)    w64p += (a[0]+a[1])+(a[2]+a[3]);
      else {
        #pragma unroll
        for (int i=0;i<4;i++){
          int raw = kc0 + t*16 + g*4 + i - q;
          if (raw <= -32) w0p += a[i];
          else if (raw >= 32) w64p += a[i];
          else wrow[c][raw+32] = a[i];   // raw+32 in 1..63: slot 0 stays zero
        }
      }
    }
  }
  w0p += __shfl_xor(w0p, 16, 64); w64p += __shfl_xor(w64p, 16, 64);
  w0p += __shfl_xor(w0p, 32, 64); w64p += __shfl_xor(w64p, 32, 64);
  if (g == 0) red[wave*16 + c] = make_float2(w0p, w64p);   // slots 0..63 (last Newton used 64..127)
  __syncthreads();                                         // B6: wrow+attn_l+red ready

  // PV: wave owns d-cols [wave*16,+16), full K=1024; first 8 tiles from vf regs; dual accumulator
  f4v acc0 = {}, acc1 = {};
  __builtin_amdgcn_s_setprio(1);
  #pragma unroll
  for (int kk=0; kk<8; kk+=2){
    s8v af0 = *(const s8v*)(&attn_l[c][kk*32 + g*8]);
    acc0 = __builtin_amdgcn_mfma_f32_16x16x32_bf16(af0, vf[kk], acc0, 0,0,0);
    s8v af1 = *(const s8v*)(&attn_l[c][(kk+1)*32 + g*8]);
    acc1 = __builtin_amdgcn_mfma_f32_16x16x32_bf16(af1, vf[kk+1], acc1, 0,0,0);
  }
  #pragma unroll
  for (int kk=8; kk<32; kk+=2){
    s8v af0 = *(const s8v*)(&attn_l[c][kk*32 + g*8]);
    s8v bf0 = *(const s8v*)(Vh + (size_t)(wave*16+c)*1024 + kk*32 + g*8);
    acc0 = __builtin_amdgcn_mfma_f32_16x16x32_bf16(af0, bf0, acc0, 0,0,0);
    s8v af1 = *(const s8v*)(&attn_l[c][(kk+1)*32 + g*8]);
    s8v bf1 = *(const s8v*)(Vh + (size_t)(wave*16+c)*1024 + (kk+1)*32 + g*8);
    acc1 = __builtin_amdgcn_mfma_f32_16x16x32_bf16(af1, bf1, acc1, 0,0,0);
  }
  f4v acc = acc0 + acc1;
  {
    const float* wp = &wrow[c][0];
    f4v A0 = *(const f4v*)(wp + g*8);
    f4v A1 = *(const f4v*)(wp + g*8 + 4);
    f4v A2 = *(const f4v*)(wp + 32 + g*8);
    f4v A3 = *(const f4v*)(wp + 32 + g*8 + 4);
    union { unsigned u[4]; s8v v; } W0, W1;
    asm("v_cvt_pk_bf16_f32 %0, %1, %2" : "=v"(W0.u[0]) : "v"(A0[0]), "v"(A0[1]));
    asm("v_cvt_pk_bf16_f32 %0, %1, %2" : "=v"(W0.u[1]) : "v"(A0[2]), "v"(A0[3]));
    asm("v_cvt_pk_bf16_f32 %0, %1, %2" : "=v"(W0.u[2]) : "v"(A1[0]), "v"(A1[1]));
    asm("v_cvt_pk_bf16_f32 %0, %1, %2" : "=v"(W0.u[3]) : "v"(A1[2]), "v"(A1[3]));
    asm("v_cvt_pk_bf16_f32 %0, %1, %2" : "=v"(W1.u[0]) : "v"(A2[0]), "v"(A2[1]));
    asm("v_cvt_pk_bf16_f32 %0, %1, %2" : "=v"(W1.u[1]) : "v"(A2[2]), "v"(A2[3]));
    asm("v_cvt_pk_bf16_f32 %0, %1, %2" : "=v"(W1.u[2]) : "v"(A3[0]), "v"(A3[1]));
    asm("v_cvt_pk_bf16_f32 %0, %1, %2" : "=v"(W1.u[3]) : "v"(A3[2]), "v"(A3[3]));
    s8v rb0 = *(const s8v*)(relT + (wave*16+c)*72 + g*8);
    s8v rb1 = *(const s8v*)(relT + (wave*16+c)*72 + 32 + g*8);
    acc = __builtin_amdgcn_mfma_f32_16x16x32_bf16(W0.v, rb0, acc, 0,0,0);
    acc = __builtin_amdgcn_mfma_f32_16x16x32_bf16(W1.v, rb1, acc, 0,0,0);
  }
  __builtin_amdgcn_s_setprio(0);

  // store: add j=0 and j=64 bucket terms, apply global 0.25 scale (undoes the 4x attn')
  int b = bh >> 4, h = bh & 15, d = wave*16 + c;
  float rl0  = bf2f(relT[d*72 + 0]);
  float rl64 = bf2f(relT[d*72 + 64]);
  #pragma unroll
  for (int i=0;i<4;i++){
    int r = g*4+i;
    float2 p0 = red[r], p1 = red[16+r], p2 = red[32+r], p3 = red[48+r];
    float w0 = (p0.x+p1.x)+(p2.x+p3.x);
    float w64v = (p0.y+p1.y)+(p2.y+p3.y);
    float s = 0.25f*(acc[i] + w0*rl0 + w64v*rl64);
    ctxb[((size_t)(b*1024 + q0 + r))*1024 + h*64 + d] = f2bf(s);
  }
}

extern "C" void kernel_launch(void* const* d_in, const int* in_sizes, int n_in,
                              void* d_out, int out_size, void* d_ws, size_t ws_size,
                              hipStream_t stream) {
  (void)in_sizes; (void)n_in; (void)out_size; (void)ws_size;
  const float* x    = (const float*)d_in[0];
  const float* w_q  = (const float*)d_in[1];
  const float* b_q  = (const float*)d_in[2];
  const float* w_k  = (const float*)d_in[3];
  const float* b_k  = (const float*)d_in[4];
  const float* w_v  = (const float*)d_in[5];
  const float* b_v  = (const float*)d_in[6];
  const float* w_o  = (const float*)d_in[7];
  const float* b_o  = (const float*)d_in[8];
  const float* rel  = (const float*)d_in[9];
  const float* rcos = (const float*)d_in[10];
  const float* rsin = (const float*)d_in[11];
  float* out = (float*)d_out;

  char* w = (char*)d_ws;
  short* xb    = (short*)(w);                        // 4 MiB
  short* wqkvT = (short*)(w + ((size_t)4<<20));      // 6 MiB  [3072][1024]
  short* woT   = (short*)(w + ((size_t)10<<20));     // 2 MiB
  short* Qb    = (short*)(w + ((size_t)12<<20));     // 4 MiB
  short* Kb    = (short*)(w + ((size_t)16<<20));     // 4 MiB
  short* Vt    = (short*)(w + ((size_t)20<<20));     // 4 MiB
  short* ctxb  = (short*)(w + ((size_t)24<<20));     // 4 MiB
  short* relb  = (short*)(w + ((size_t)28<<20));     // 8.3 KB
  short* relT  = (short*)(w + ((size_t)28<<20) + 65536); // 9.2 KB

  prep_k<<<dim3(16,16,6), 256, 0, stream>>>(w_q, w_k, w_v, w_o, x, rel, wqkvT, woT, xb, relb, relT);
  gemm_qkv_k<<<768, 256, 0, stream>>>(xb, wqkvT, b_q, b_k, b_v, rcos, rsin, Qb, Kb, Vt);
  attn_fused_k<<<2048, 256, 0, stream>>>(Qb, Kb, relb, relT, Vt, ctxb);
  gemm_out_k<<<512, 256, 0, stream>>>(ctxb, woT, b_o, out);
}